// Round 6
// baseline (752.840 us; speedup 1.0000x reference)
//
#include <hip/hip_runtime.h>

// Problem dims (fixed by the reference)
#define NN      2048
#define IN_DIM  784
#define NFEAT   100
#define NP      2000   // MW*MP
#define NS      30
#define OUTC    2100   // NFEAT + NP
#define NWIN    6      // 8-bit windows covering bits 2^-4 .. 2^-51

typedef double f64x4  __attribute__((ext_vector_type(4)));
typedef float  f32x4  __attribute__((ext_vector_type(4)));
typedef short  bf16x8 __attribute__((ext_vector_type(8)));

__device__ __forceinline__ f64x4 mfma_f64(double a, double b, f64x4 c) {
#if __has_builtin(__builtin_amdgcn_mfma_f64_16x16x4f64)
    return __builtin_amdgcn_mfma_f64_16x16x4f64(a, b, c, 0, 0, 0);
#else
    asm volatile("v_mfma_f64_16x16x4_f64 %0, %1, %2, %0"
                 : "+v"(c) : "v"(a), "v"(b));
    return c;
#endif
}

// ---------------------------------------------------------------------------
// Kernel 1: feature layer + Bernoulli rate coding (f64 decisions). Unchanged.
// ---------------------------------------------------------------------------
__global__ __launch_bounds__(256) void sbls_k1(
    const float* __restrict__ X, const float* __restrict__ W1,
    const float* __restrict__ B1, const float* __restrict__ U,
    float* __restrict__ out, unsigned* __restrict__ colmask)
{
    int tid = blockIdx.x * blockDim.x + threadIdx.x;
    if (tid >= NN * NFEAT) return;
    int n = tid / NFEAT;
    int f = tid - n * NFEAT;

    const float* xr = X + (size_t)n * IN_DIM;
    double acc = (double)B1[f];
    for (int k = 0; k < IN_DIM; ++k)
        acc += (double)xr[k] * (double)W1[k * NFEAT + f];

    double z = 1.0 / (1.0 + exp(-acc / 3.0));

    unsigned m = 0;
    int cnt = 0;
    for (int s = 0; s < NS; ++s) {
        float u = U[(size_t)s * (NN * NFEAT) + tid];
        int sp = ((double)u < z) ? 1 : 0;
        m |= (unsigned)sp << s;
        cnt += sp;
    }
    colmask[tid] = m;
    out[(size_t)n * OUTC + f] = (float)((double)cnt / 30.0);
}

// ---------------------------------------------------------------------------
// Slicer: W2 (f32, (NFEAT,NP)) -> 6 bf16 windows, transposed [w][p][f-pad128].
// w = sum_j sign(w)*int_j*2^-(11+8j), int_j in [0,255]; all ops exact in f64;
// each slice has <=8 significant bits -> exact in bf16. Truncation < 2^-51.
// ---------------------------------------------------------------------------
__global__ __launch_bounds__(256) void sbls_slice(
    const float* __restrict__ W2, unsigned short* __restrict__ slt)
{
    int idx = blockIdx.x * blockDim.x + threadIdx.x;
    if (idx >= NP * 128) return;
    int f = idx & 127;
    int p = idx >> 7;

    double w = (f < NFEAT) ? (double)W2[(size_t)f * NP + p] : 0.0;
    double aw = fabs(w);
    double sg = (w < 0.0) ? -1.0 : 1.0;
    double r = aw;
    const double scale[NWIN] = {0x1p11, 0x1p19, 0x1p27, 0x1p35, 0x1p43, 0x1p51};
#pragma unroll
    for (int j = 0; j < NWIN; ++j) {
        double t = floor(r * scale[j]);          // integer in [0,255], exact
        r = r - t / scale[j];                     // exact (power-of-2 grid)
        float v = (float)(sg * t / scale[j]);     // <=8 sig bits -> exact
        unsigned u = __builtin_bit_cast(unsigned, v);
        slt[((size_t)j * NP + p) * 128 + f] = (unsigned short)(u >> 16);
    }
}

// ---------------------------------------------------------------------------
// Kernel 2 (bf16 engine): h[s][p] = sum_f K[s][f]*W2[f][p] reconstructed
// exactly from 3 window-pair f32 MFMA accumulators (each pair chains two
// 8-bit windows exactly: integers < 2^23 on a common grid). Skeleton (grid,
// smask, LDS-transpose epilogue, f64 LIF) identical to the verified round-5
// kernel. Fragment layout = m89-verified bf16 16x16x32 mapping:
//   A[m= l&15][k = (l>>4)*8+j], B[k][n= l&15], D[row=(l>>4)*4+r][col=l&15].
// A/B share the same (group,j)->k labeling, so any hardware k-permutation
// cancels by bijection.
// ---------------------------------------------------------------------------
__global__ __launch_bounds__(256, 2) void sbls_k2_bf16(
    const unsigned short* __restrict__ slt,  // [6][NP][128] bf16 slices
    const float*    __restrict__ B2,
    const unsigned* __restrict__ colmask,
    float*          __restrict__ out)
{
    __shared__ unsigned smask[NFEAT];
    __shared__ double h_lds[32][130];

    const int n     = blockIdx.x;
    const int chunk = blockIdx.y;            // 0..7
    const int l  = threadIdx.x & 63;
    const int wv = threadIdx.x >> 6;
    const int lm = l & 15;
    const int lg = l >> 4;

    if (threadIdx.x < NFEAT)
        smask[threadIdx.x] = colmask[n * NFEAT + threadIdx.x];
    __syncthreads();

    // A-fragments: K-selector bits as bf16 {0,1}; f padded 100->128 with 0.
    bf16x8 afr[2][4];
#pragma unroll
    for (int kt = 0; kt < 4; ++kt)
#pragma unroll
        for (int j = 0; j < 8; ++j) {
            int f = kt * 32 + lg * 8 + j;
            unsigned mv = (f < NFEAT) ? smask[f] : 0u;
            afr[0][kt][j] = (short)(((mv >> lm) & 1u) ? 0x3F80 : 0);
            afr[1][kt][j] = (short)(((mv >> (lm + 16)) & 1u) ? 0x3F80 : 0);
        }

    int prow[4];
#pragma unroll
    for (int i = 0; i < 4; ++i) {
        int p = chunk * 256 + (wv * 4 + i) * 16 + lm;
        prow[i] = (p < NP) ? p : (NP - 1);
    }

    f32x4 acc[3][2][4];
#pragma unroll
    for (int wp = 0; wp < 3; ++wp)
#pragma unroll
        for (int st = 0; st < 2; ++st)
#pragma unroll
            for (int i = 0; i < 4; ++i)
                acc[wp][st][i] = (f32x4){0.f, 0.f, 0.f, 0.f};

#pragma unroll
    for (int wp = 0; wp < 3; ++wp) {
#pragma unroll
        for (int ww = 0; ww < 2; ++ww) {
            const int w = wp * 2 + ww;
#pragma unroll
            for (int kt = 0; kt < 4; ++kt) {
#pragma unroll
                for (int i = 0; i < 4; ++i) {
                    const bf16x8 b = *(const bf16x8*)(
                        slt + ((size_t)w * NP + prow[i]) * 128 + kt * 32 + lg * 8);
                    acc[wp][0][i] = __builtin_amdgcn_mfma_f32_16x16x32_bf16(
                        afr[0][kt], b, acc[wp][0][i], 0, 0, 0);
                    acc[wp][1][i] = __builtin_amdgcn_mfma_f32_16x16x32_bf16(
                        afr[1][kt], b, acc[wp][1][i], 0, 0, 0);
                }
            }
        }
    }

    // Epilogue: combine 3 exact f32 partials in f64 during the LDS transpose,
    // then the round-5-verified sequential f64 LIF per p.
#pragma unroll
    for (int hp = 0; hp < 2; ++hp) {
        __syncthreads();
        if ((wv >> 1) == hp) {
#pragma unroll
            for (int i = 0; i < 4; ++i) {
                int tloc = (wv & 1) * 4 + i;
#pragma unroll
                for (int st = 0; st < 2; ++st)
#pragma unroll
                    for (int r = 0; r < 4; ++r) {
                        double hv = (double)acc[0][st][i][r]
                                  + (double)acc[1][st][i][r]
                                  + (double)acc[2][st][i][r];
                        h_lds[st * 16 + lg * 4 + r][tloc * 16 + lm] = hv;
                    }
            }
        }
        __syncthreads();
        if (threadIdx.x < 128) {
            int p = chunk * 256 + hp * 128 + threadIdx.x;
            if (p < NP) {
                double b2d = (double)B2[p];
                double mem = 0.0, spk = 0.0;
                int cnt = 0;
#pragma unroll
                for (int s = 0; s < NS; ++s) {
                    double h = h_lds[s][threadIdx.x] + b2d;
                    mem = 0.9 * mem + h - spk;
                    bool sp = mem > 1.0;
                    spk = sp ? 1.0 : 0.0;
                    cnt += sp;
                }
                out[(size_t)n * OUTC + NFEAT + p] = (float)((double)cnt / 30.0);
            }
        }
    }
}

// ---------------------------------------------------------------------------
// Fallback kernel 2 (round-5 f64 MFMA, probed layout) — used if ws too small.
// ---------------------------------------------------------------------------
__global__ __launch_bounds__(256, 2) void sbls_k2_f64(
    const float*    __restrict__ W2, const float* __restrict__ B2,
    const unsigned* __restrict__ colmask, float* __restrict__ out)
{
    __shared__ unsigned smask[NFEAT];
    __shared__ double h_lds[32][130];

    const int n     = blockIdx.x;
    const int chunk = blockIdx.y;
    const int l  = threadIdx.x & 63;
    const int wv = threadIdx.x >> 6;
    const int lm = l & 15;
    const int lg = l >> 4;

    if (threadIdx.x < NFEAT)
        smask[threadIdx.x] = colmask[n * NFEAT + threadIdx.x];

    f64x4 zero = (f64x4){0.0, 0.0, 0.0, 0.0};
    f64x4 d1 = mfma_f64((double)lm, 1.0, zero);
    f64x4 d2 = mfma_f64(1.0, (double)lm, zero);
    int srow[4], pcol[4];
#pragma unroll
    for (int r = 0; r < 4; ++r) {
        int a = (int)(d1[r] * 0.25);
        int b = (int)(d2[r] * 0.25);
        srow[r] = (a < 0) ? 0 : (a > 15 ? 15 : a);
        pcol[r] = (b < 0) ? 0 : (b > 15 ? 15 : b);
    }
    __syncthreads();

    f64x4 acc[2][4];
    int pclamp[4];
#pragma unroll
    for (int i = 0; i < 4; ++i) {
        int p = chunk * 256 + (wv * 4 + i) * 16 + lm;
        pclamp[i] = (p < NP) ? p : (NP - 1);
        acc[0][i] = zero; acc[1][i] = zero;
    }
    for (int kt = 0; kt < 25; ++kt) {
        unsigned mw = smask[kt * 4 + lg];
        double a0 = ((mw >> lm) & 1u) ? 1.0 : 0.0;
        double a1 = ((mw >> (lm + 16)) & 1u) ? 1.0 : 0.0;
        const float* wrow = W2 + (size_t)(kt * 4 + lg) * NP;
#pragma unroll
        for (int i = 0; i < 4; ++i) {
            double b = (double)wrow[pclamp[i]];
            acc[0][i] = mfma_f64(a0, b, acc[0][i]);
            acc[1][i] = mfma_f64(a1, b, acc[1][i]);
        }
    }
#pragma unroll
    for (int hp = 0; hp < 2; ++hp) {
        __syncthreads();
        if ((wv >> 1) == hp) {
#pragma unroll
            for (int i = 0; i < 4; ++i) {
                int tloc = (wv & 1) * 4 + i;
#pragma unroll
                for (int st = 0; st < 2; ++st)
#pragma unroll
                    for (int r = 0; r < 4; ++r)
                        h_lds[st * 16 + srow[r]][tloc * 16 + pcol[r]] = acc[st][i][r];
            }
        }
        __syncthreads();
        if (threadIdx.x < 128) {
            int p = chunk * 256 + hp * 128 + threadIdx.x;
            if (p < NP) {
                double b2d = (double)B2[p];
                double mem = 0.0, spk = 0.0;
                int cnt = 0;
#pragma unroll
                for (int s = 0; s < NS; ++s) {
                    double h = h_lds[s][threadIdx.x] + b2d;
                    mem = 0.9 * mem + h - spk;
                    bool sp = mem > 1.0;
                    spk = sp ? 1.0 : 0.0;
                    cnt += sp;
                }
                out[(size_t)n * OUTC + NFEAT + p] = (float)((double)cnt / 30.0);
            }
        }
    }
}

// ---------------------------------------------------------------------------
extern "C" void kernel_launch(void* const* d_in, const int* in_sizes, int n_in,
                              void* d_out, int out_size, void* d_ws, size_t ws_size,
                              hipStream_t stream) {
    const float* X  = (const float*)d_in[0];
    const float* W1 = (const float*)d_in[1];
    const float* B1 = (const float*)d_in[2];
    const float* W2 = (const float*)d_in[3];
    const float* B2 = (const float*)d_in[4];
    const float* U  = (const float*)d_in[5];
    float* out = (float*)d_out;

    unsigned* colmask = (unsigned*)d_ws;                    // 819,200 B
    const size_t SLT_OFF = 1u << 20;                        // 1 MiB
    const size_t SLT_BYTES = (size_t)NWIN * NP * 128 * 2;   // 3,072,000 B
    unsigned short* slt = (unsigned short*)((char*)d_ws + SLT_OFF);
    bool use_bf16 = (ws_size >= SLT_OFF + SLT_BYTES);

    {
        int total = NN * NFEAT;
        sbls_k1<<<(total + 255) / 256, 256, 0, stream>>>(X, W1, B1, U, out, colmask);
    }
    if (use_bf16) {
        int total = NP * 128;
        sbls_slice<<<(total + 255) / 256, 256, 0, stream>>>(W2, slt);
        dim3 grid(NN, (NP + 255) / 256);
        sbls_k2_bf16<<<grid, 256, 0, stream>>>(slt, B2, colmask, out);
    } else {
        dim3 grid(NN, (NP + 255) / 256);
        sbls_k2_f64<<<grid, 256, 0, stream>>>(W2, B2, colmask, out);
    }
}

// Round 7
// 662.995 us; speedup vs baseline: 1.1355x; 1.1355x over previous
//
#include <hip/hip_runtime.h>

// Problem dims (fixed by the reference)
#define NN      2048
#define IN_DIM  784
#define NFEAT   100
#define NP      2000   // MW*MP
#define NS      30
#define OUTC    2100   // NFEAT + NP
#define NWIN    6      // 8-bit windows covering bits 2^-4 .. 2^-51
#define G       4      // n-batch per block
#define CHUNK   64     // p per block

typedef double f64x4  __attribute__((ext_vector_type(4)));
typedef float  f32x4  __attribute__((ext_vector_type(4)));
typedef short  bf16x8 __attribute__((ext_vector_type(8)));

__device__ __forceinline__ f64x4 mfma_f64(double a, double b, f64x4 c) {
#if __has_builtin(__builtin_amdgcn_mfma_f64_16x16x4f64)
    return __builtin_amdgcn_mfma_f64_16x16x4f64(a, b, c, 0, 0, 0);
#else
    asm volatile("v_mfma_f64_16x16x4_f64 %0, %1, %2, %0"
                 : "+v"(c) : "v"(a), "v"(b));
    return c;
#endif
}

// ---------------------------------------------------------------------------
// Kernel 1: feature layer + Bernoulli rate coding (f64 decisions). Unchanged.
// ---------------------------------------------------------------------------
__global__ __launch_bounds__(256) void sbls_k1(
    const float* __restrict__ X, const float* __restrict__ W1,
    const float* __restrict__ B1, const float* __restrict__ U,
    float* __restrict__ out, unsigned* __restrict__ colmask)
{
    int tid = blockIdx.x * blockDim.x + threadIdx.x;
    if (tid >= NN * NFEAT) return;
    int n = tid / NFEAT;
    int f = tid - n * NFEAT;

    const float* xr = X + (size_t)n * IN_DIM;
    double acc = (double)B1[f];
    for (int k = 0; k < IN_DIM; ++k)
        acc += (double)xr[k] * (double)W1[k * NFEAT + f];

    double z = 1.0 / (1.0 + exp(-acc / 3.0));

    unsigned m = 0;
    int cnt = 0;
    for (int s = 0; s < NS; ++s) {
        float u = U[(size_t)s * (NN * NFEAT) + tid];
        int sp = ((double)u < z) ? 1 : 0;
        m |= (unsigned)sp << s;
        cnt += sp;
    }
    colmask[tid] = m;
    out[(size_t)n * OUTC + f] = (float)((double)cnt / 30.0);
}

// ---------------------------------------------------------------------------
// Slicer: W2 (f32, (NFEAT,NP)) -> 6 bf16 windows, transposed [w][p][f-pad128].
// Unchanged from the round-6-verified version (absmax 0.0).
// ---------------------------------------------------------------------------
__global__ __launch_bounds__(256) void sbls_slice(
    const float* __restrict__ W2, unsigned short* __restrict__ slt)
{
    int idx = blockIdx.x * blockDim.x + threadIdx.x;
    if (idx >= NP * 128) return;
    int f = idx & 127;
    int p = idx >> 7;

    double w = (f < NFEAT) ? (double)W2[(size_t)f * NP + p] : 0.0;
    double aw = fabs(w);
    double sg = (w < 0.0) ? -1.0 : 1.0;
    double r = aw;
    const double scale[NWIN] = {0x1p11, 0x1p19, 0x1p27, 0x1p35, 0x1p43, 0x1p51};
#pragma unroll
    for (int j = 0; j < NWIN; ++j) {
        double t = floor(r * scale[j]);          // integer in [0,255], exact
        r = r - t / scale[j];                     // exact (power-of-2 grid)
        float v = (float)(sg * t / scale[j]);     // <=8 sig bits -> exact
        unsigned u = __builtin_bit_cast(unsigned, v);
        slt[((size_t)j * NP + p) * 128 + f] = (unsigned short)(u >> 16);
    }
}

// ---------------------------------------------------------------------------
// Kernel 2 (v7): n-batched bf16 MFMA GEMM + fused LIF.
// Per block: G=4 batch rows, CHUNK=64 p-columns. A-selector fragments for
// all (kt,n,st) are prebuilt once into a 32 KB LDS table (identical bit->
// bf16 construction to the round-6-verified kernel). Main loop is kt-outer:
// 8 A-frags register-resident per kt; each B-load (one 16B global read per
// (w,kt)) feeds 8 MFMAs (4n x 2st) -> MFMA:load = 8:1 (was 2:1), and B
// L2-traffic drops 4x. All accumulation remains integer-exact in f32 pairs,
// combined in f64 at the epilogue (proven absmax 0.0 path).
// ---------------------------------------------------------------------------
__global__ __launch_bounds__(256, 3) void sbls_k2_bf16(
    const unsigned short* __restrict__ slt,  // [6][NP][128] bf16 slices
    const float*    __restrict__ B2,
    const unsigned* __restrict__ colmask,
    float*          __restrict__ out)
{
    __shared__ unsigned smask[G][NFEAT];
    __shared__ __align__(16) unsigned short afrag[32][64][8]; // 32 KB
    __shared__ double h_lds[32][CHUNK + 2];

    const int ng    = blockIdx.x;            // n-group (0..511)
    const int chunk = blockIdx.y;            // 0..31
    const int t  = threadIdx.x;
    const int l  = t & 63;
    const int wv = t >> 6;
    const int lm = l & 15;
    const int lg = l >> 4;

    for (int i = t; i < G * NFEAT; i += 256)
        smask[i / NFEAT][i % NFEAT] = colmask[(ng * G + i / NFEAT) * NFEAT + (i % NFEAT)];
    __syncthreads();

    // Build A-fragment table: fid = (kt*G + n)*2 + st, per-lane 8 bf16.
    // Element j of lane L: f = kt*32 + (L>>4)*8 + j ; bit s = st*16 + (L&15).
    for (int e = t; e < 32 * 64; e += 256) {
        int fid = e >> 6, L = e & 63;
        int st = fid & 1, n = (fid >> 1) & 3, kt = fid >> 3;
        int lgE = L >> 4, lmE = L & 15;
        int s = st * 16 + lmE;
        bf16x8 v;
#pragma unroll
        for (int j = 0; j < 8; ++j) {
            int f = kt * 32 + lgE * 8 + j;
            unsigned mv = (f < NFEAT) ? smask[n][f] : 0u;
            v[j] = (short)(((mv >> s) & 1u) ? 0x3F80 : 0);
        }
        *(bf16x8*)(&afrag[fid][L][0]) = v;
    }
    __syncthreads();

    const int p = chunk * CHUNK + wv * 16 + lm;
    const int prow = (p < NP) ? p : (NP - 1);
    const unsigned short* bbase = slt + (size_t)prow * 128 + lg * 8;

    f32x4 acc[3][2][G];
#pragma unroll
    for (int wp = 0; wp < 3; ++wp)
#pragma unroll
        for (int st = 0; st < 2; ++st)
#pragma unroll
            for (int n = 0; n < G; ++n)
                acc[wp][st][n] = (f32x4){0.f, 0.f, 0.f, 0.f};

#pragma unroll
    for (int kt = 0; kt < 4; ++kt) {
        bf16x8 a[G][2];
#pragma unroll
        for (int n = 0; n < G; ++n)
#pragma unroll
            for (int st = 0; st < 2; ++st)
                a[n][st] = *(const bf16x8*)(&afrag[(kt * G + n) * 2 + st][l][0]);
#pragma unroll
        for (int w = 0; w < 6; ++w) {
            const bf16x8 b = *(const bf16x8*)(bbase + (size_t)w * NP * 128 + kt * 32);
#pragma unroll
            for (int n = 0; n < G; ++n)
#pragma unroll
                for (int st = 0; st < 2; ++st)
                    acc[w >> 1][st][n] = __builtin_amdgcn_mfma_f32_16x16x32_bf16(
                        a[n][st], b, acc[w >> 1][st][n], 0, 0, 0);
        }
    }

    // Epilogue: per n, LDS transpose + f64 LIF (round-5/6-verified path).
#pragma unroll 1
    for (int n = 0; n < G; ++n) {
        __syncthreads();
#pragma unroll
        for (int st = 0; st < 2; ++st)
#pragma unroll
            for (int r = 0; r < 4; ++r) {
                double hv = (double)acc[0][st][n][r]
                          + (double)acc[1][st][n][r]
                          + (double)acc[2][st][n][r];
                h_lds[st * 16 + lg * 4 + r][wv * 16 + lm] = hv;
            }
        __syncthreads();
        if (t < CHUNK) {
            int pp = chunk * CHUNK + t;
            if (pp < NP) {
                double b2d = (double)B2[pp];
                double mem = 0.0, spk = 0.0;
                int cnt = 0;
#pragma unroll
                for (int s = 0; s < NS; ++s) {
                    double h = h_lds[s][t] + b2d;
                    mem = 0.9 * mem + h - spk;
                    bool sp = mem > 1.0;
                    spk = sp ? 1.0 : 0.0;
                    cnt += sp;
                }
                out[(size_t)(ng * G + n) * OUTC + NFEAT + pp] = (float)((double)cnt / 30.0);
            }
        }
    }
}

// ---------------------------------------------------------------------------
// Fallback kernel 2 (round-5 f64 MFMA, probed layout) — used if ws too small.
// ---------------------------------------------------------------------------
__global__ __launch_bounds__(256, 2) void sbls_k2_f64(
    const float*    __restrict__ W2, const float* __restrict__ B2,
    const unsigned* __restrict__ colmask, float* __restrict__ out)
{
    __shared__ unsigned smask[NFEAT];
    __shared__ double h_lds[32][130];

    const int n     = blockIdx.x;
    const int chunk = blockIdx.y;
    const int l  = threadIdx.x & 63;
    const int wv = threadIdx.x >> 6;
    const int lm = l & 15;
    const int lg = l >> 4;

    if (threadIdx.x < NFEAT)
        smask[threadIdx.x] = colmask[n * NFEAT + threadIdx.x];

    f64x4 zero = (f64x4){0.0, 0.0, 0.0, 0.0};
    f64x4 d1 = mfma_f64((double)lm, 1.0, zero);
    f64x4 d2 = mfma_f64(1.0, (double)lm, zero);
    int srow[4], pcol[4];
#pragma unroll
    for (int r = 0; r < 4; ++r) {
        int a = (int)(d1[r] * 0.25);
        int b = (int)(d2[r] * 0.25);
        srow[r] = (a < 0) ? 0 : (a > 15 ? 15 : a);
        pcol[r] = (b < 0) ? 0 : (b > 15 ? 15 : b);
    }
    __syncthreads();

    f64x4 acc[2][4];
    int pclamp[4];
#pragma unroll
    for (int i = 0; i < 4; ++i) {
        int p = chunk * 256 + (wv * 4 + i) * 16 + lm;
        pclamp[i] = (p < NP) ? p : (NP - 1);
        acc[0][i] = zero; acc[1][i] = zero;
    }
    for (int kt = 0; kt < 25; ++kt) {
        unsigned mw = smask[kt * 4 + lg];
        double a0 = ((mw >> lm) & 1u) ? 1.0 : 0.0;
        double a1 = ((mw >> (lm + 16)) & 1u) ? 1.0 : 0.0;
        const float* wrow = W2 + (size_t)(kt * 4 + lg) * NP;
#pragma unroll
        for (int i = 0; i < 4; ++i) {
            double b = (double)wrow[pclamp[i]];
            acc[0][i] = mfma_f64(a0, b, acc[0][i]);
            acc[1][i] = mfma_f64(a1, b, acc[1][i]);
        }
    }
#pragma unroll
    for (int hp = 0; hp < 2; ++hp) {
        __syncthreads();
        if ((wv >> 1) == hp) {
#pragma unroll
            for (int i = 0; i < 4; ++i) {
                int tloc = (wv & 1) * 4 + i;
#pragma unroll
                for (int st = 0; st < 2; ++st)
#pragma unroll
                    for (int r = 0; r < 4; ++r)
                        h_lds[st * 16 + srow[r]][tloc * 16 + pcol[r]] = acc[st][i][r];
            }
        }
        __syncthreads();
        if (threadIdx.x < 128) {
            int p = chunk * 256 + hp * 128 + threadIdx.x;
            if (p < NP) {
                double b2d = (double)B2[p];
                double mem = 0.0, spk = 0.0;
                int cnt = 0;
#pragma unroll
                for (int s = 0; s < NS; ++s) {
                    double h = h_lds[s][threadIdx.x] + b2d;
                    mem = 0.9 * mem + h - spk;
                    bool sp = mem > 1.0;
                    spk = sp ? 1.0 : 0.0;
                    cnt += sp;
                }
                out[(size_t)n * OUTC + NFEAT + p] = (float)((double)cnt / 30.0);
            }
        }
    }
}

// ---------------------------------------------------------------------------
extern "C" void kernel_launch(void* const* d_in, const int* in_sizes, int n_in,
                              void* d_out, int out_size, void* d_ws, size_t ws_size,
                              hipStream_t stream) {
    const float* X  = (const float*)d_in[0];
    const float* W1 = (const float*)d_in[1];
    const float* B1 = (const float*)d_in[2];
    const float* W2 = (const float*)d_in[3];
    const float* B2 = (const float*)d_in[4];
    const float* U  = (const float*)d_in[5];
    float* out = (float*)d_out;

    unsigned* colmask = (unsigned*)d_ws;                    // 819,200 B
    const size_t SLT_OFF = 1u << 20;                        // 1 MiB
    const size_t SLT_BYTES = (size_t)NWIN * NP * 128 * 2;   // 3,072,000 B
    unsigned short* slt = (unsigned short*)((char*)d_ws + SLT_OFF);
    bool use_bf16 = (ws_size >= SLT_OFF + SLT_BYTES);

    {
        int total = NN * NFEAT;
        sbls_k1<<<(total + 255) / 256, 256, 0, stream>>>(X, W1, B1, U, out, colmask);
    }
    if (use_bf16) {
        int total = NP * 128;
        sbls_slice<<<(total + 255) / 256, 256, 0, stream>>>(W2, slt);
        dim3 grid(NN / G, (NP + CHUNK - 1) / CHUNK);        // 512 x 32
        sbls_k2_bf16<<<grid, 256, 0, stream>>>(slt, B2, colmask, out);
    } else {
        dim3 grid(NN, (NP + 255) / 256);
        sbls_k2_f64<<<grid, 256, 0, stream>>>(W2, B2, colmask, out);
    }
}

// Round 8
// 632.182 us; speedup vs baseline: 1.1909x; 1.0487x over previous
//
#include <hip/hip_runtime.h>

// Problem dims (fixed by the reference)
#define NN      2048
#define IN_DIM  784
#define NFEAT   100
#define NP      2000   // MW*MP
#define NS      30
#define OUTC    2100   // NFEAT + NP
#define NWIN    6      // 8-bit windows covering bits 2^-4 .. 2^-51
#define G       4      // n-batch per block
#define CHUNK   64     // p per block

typedef double f64x4  __attribute__((ext_vector_type(4)));
typedef float  f32x4  __attribute__((ext_vector_type(4)));
typedef short  bf16x8 __attribute__((ext_vector_type(8)));

__device__ __forceinline__ f64x4 mfma_f64(double a, double b, f64x4 c) {
#if __has_builtin(__builtin_amdgcn_mfma_f64_16x16x4f64)
    return __builtin_amdgcn_mfma_f64_16x16x4f64(a, b, c, 0, 0, 0);
#else
    asm volatile("v_mfma_f64_16x16x4_f64 %0, %1, %2, %0"
                 : "+v"(c) : "v"(a), "v"(b));
    return c;
#endif
}

// ---------------------------------------------------------------------------
// Kernel 1: feature layer + Bernoulli rate coding (f64 decisions). Unchanged.
// ---------------------------------------------------------------------------
__global__ __launch_bounds__(256) void sbls_k1(
    const float* __restrict__ X, const float* __restrict__ W1,
    const float* __restrict__ B1, const float* __restrict__ U,
    float* __restrict__ out, unsigned* __restrict__ colmask)
{
    int tid = blockIdx.x * blockDim.x + threadIdx.x;
    if (tid >= NN * NFEAT) return;
    int n = tid / NFEAT;
    int f = tid - n * NFEAT;

    const float* xr = X + (size_t)n * IN_DIM;
    double acc = (double)B1[f];
    for (int k = 0; k < IN_DIM; ++k)
        acc += (double)xr[k] * (double)W1[k * NFEAT + f];

    double z = 1.0 / (1.0 + exp(-acc / 3.0));

    unsigned m = 0;
    int cnt = 0;
    for (int s = 0; s < NS; ++s) {
        float u = U[(size_t)s * (NN * NFEAT) + tid];
        int sp = ((double)u < z) ? 1 : 0;
        m |= (unsigned)sp << s;
        cnt += sp;
    }
    colmask[tid] = m;
    out[(size_t)n * OUTC + f] = (float)((double)cnt / 30.0);
}

// ---------------------------------------------------------------------------
// Slicer: W2 (f32, (NFEAT,NP)) -> 6 bf16 windows, transposed [w][p][f-pad128].
// Unchanged from the round-6-verified version (absmax 0.0).
// ---------------------------------------------------------------------------
__global__ __launch_bounds__(256) void sbls_slice(
    const float* __restrict__ W2, unsigned short* __restrict__ slt)
{
    int idx = blockIdx.x * blockDim.x + threadIdx.x;
    if (idx >= NP * 128) return;
    int f = idx & 127;
    int p = idx >> 7;

    double w = (f < NFEAT) ? (double)W2[(size_t)f * NP + p] : 0.0;
    double aw = fabs(w);
    double sg = (w < 0.0) ? -1.0 : 1.0;
    double r = aw;
    const double scale[NWIN] = {0x1p11, 0x1p19, 0x1p27, 0x1p35, 0x1p43, 0x1p51};
#pragma unroll
    for (int j = 0; j < NWIN; ++j) {
        double t = floor(r * scale[j]);          // integer in [0,255], exact
        r = r - t / scale[j];                     // exact (power-of-2 grid)
        float v = (float)(sg * t / scale[j]);     // <=8 sig bits -> exact
        unsigned u = __builtin_bit_cast(unsigned, v);
        slt[((size_t)j * NP + p) * 128 + f] = (unsigned short)(u >> 16);
    }
}

// ---------------------------------------------------------------------------
// Kernel 2 (v8): n-batched bf16 MFMA GEMM + fused LIF.
// Identical structure to round 7 (G=4 n-batch, CHUNK=64, kt-outer loop,
// 8:1 MFMA:B-load ratio) but launch_bounds back to (256,2): round 7's
// (256,3) capped arch-VGPRs at 84 -> scratch spill -> 0.9-1.7 GB/dispatch
// HBM traffic. At (256,2) round 6 measured VGPR 120, zero spill.
// All math integer-exact as proven (absmax 0.0 in rounds 6 and 7).
// ---------------------------------------------------------------------------
__global__ __launch_bounds__(256, 2) void sbls_k2_bf16(
    const unsigned short* __restrict__ slt,  // [6][NP][128] bf16 slices
    const float*    __restrict__ B2,
    const unsigned* __restrict__ colmask,
    float*          __restrict__ out)
{
    __shared__ unsigned smask[G][NFEAT];
    __shared__ __align__(16) unsigned short afrag[32][64][8]; // 32 KB
    __shared__ double h_lds[32][CHUNK + 2];

    const int ng    = blockIdx.x;            // n-group (0..511)
    const int chunk = blockIdx.y;            // 0..31
    const int t  = threadIdx.x;
    const int l  = t & 63;
    const int wv = t >> 6;
    const int lm = l & 15;
    const int lg = l >> 4;

    for (int i = t; i < G * NFEAT; i += 256)
        smask[i / NFEAT][i % NFEAT] = colmask[(ng * G + i / NFEAT) * NFEAT + (i % NFEAT)];
    __syncthreads();

    // Build A-fragment table: fid = (kt*G + n)*2 + st, per-lane 8 bf16.
    // Element j of lane L: f = kt*32 + (L>>4)*8 + j ; bit s = st*16 + (L&15).
    for (int e = t; e < 32 * 64; e += 256) {
        int fid = e >> 6, L = e & 63;
        int st = fid & 1, n = (fid >> 1) & 3, kt = fid >> 3;
        int lgE = L >> 4, lmE = L & 15;
        int s = st * 16 + lmE;
        bf16x8 v;
#pragma unroll
        for (int j = 0; j < 8; ++j) {
            int f = kt * 32 + lgE * 8 + j;
            unsigned mv = (f < NFEAT) ? smask[n][f] : 0u;
            v[j] = (short)(((mv >> s) & 1u) ? 0x3F80 : 0);
        }
        *(bf16x8*)(&afrag[fid][L][0]) = v;
    }
    __syncthreads();

    const int p = chunk * CHUNK + wv * 16 + lm;
    const int prow = (p < NP) ? p : (NP - 1);
    const unsigned short* bbase = slt + (size_t)prow * 128 + lg * 8;

    f32x4 acc[3][2][G];
#pragma unroll
    for (int wp = 0; wp < 3; ++wp)
#pragma unroll
        for (int st = 0; st < 2; ++st)
#pragma unroll
            for (int n = 0; n < G; ++n)
                acc[wp][st][n] = (f32x4){0.f, 0.f, 0.f, 0.f};

#pragma unroll
    for (int kt = 0; kt < 4; ++kt) {
        bf16x8 a[G][2];
#pragma unroll
        for (int n = 0; n < G; ++n)
#pragma unroll
            for (int st = 0; st < 2; ++st)
                a[n][st] = *(const bf16x8*)(&afrag[(kt * G + n) * 2 + st][l][0]);
#pragma unroll
        for (int w = 0; w < 6; ++w) {
            const bf16x8 b = *(const bf16x8*)(bbase + (size_t)w * NP * 128 + kt * 32);
#pragma unroll
            for (int n = 0; n < G; ++n)
#pragma unroll
                for (int st = 0; st < 2; ++st)
                    acc[w >> 1][st][n] = __builtin_amdgcn_mfma_f32_16x16x32_bf16(
                        a[n][st], b, acc[w >> 1][st][n], 0, 0, 0);
        }
    }

    // Epilogue: per n, LDS transpose + f64 LIF (round-5/6-verified path).
#pragma unroll 1
    for (int n = 0; n < G; ++n) {
        __syncthreads();
#pragma unroll
        for (int st = 0; st < 2; ++st)
#pragma unroll
            for (int r = 0; r < 4; ++r) {
                double hv = (double)acc[0][st][n][r]
                          + (double)acc[1][st][n][r]
                          + (double)acc[2][st][n][r];
                h_lds[st * 16 + lg * 4 + r][wv * 16 + lm] = hv;
            }
        __syncthreads();
        if (t < CHUNK) {
            int pp = chunk * CHUNK + t;
            if (pp < NP) {
                double b2d = (double)B2[pp];
                double mem = 0.0, spk = 0.0;
                int cnt = 0;
#pragma unroll
                for (int s = 0; s < NS; ++s) {
                    double h = h_lds[s][t] + b2d;
                    mem = 0.9 * mem + h - spk;
                    bool sp = mem > 1.0;
                    spk = sp ? 1.0 : 0.0;
                    cnt += sp;
                }
                out[(size_t)(ng * G + n) * OUTC + NFEAT + pp] = (float)((double)cnt / 30.0);
            }
        }
    }
}

// ---------------------------------------------------------------------------
// Fallback kernel 2 (round-5 f64 MFMA, probed layout) — used if ws too small.
// ---------------------------------------------------------------------------
__global__ __launch_bounds__(256, 2) void sbls_k2_f64(
    const float*    __restrict__ W2, const float* __restrict__ B2,
    const unsigned* __restrict__ colmask, float* __restrict__ out)
{
    __shared__ unsigned smask[NFEAT];
    __shared__ double h_lds[32][130];

    const int n     = blockIdx.x;
    const int chunk = blockIdx.y;
    const int l  = threadIdx.x & 63;
    const int wv = threadIdx.x >> 6;
    const int lm = l & 15;
    const int lg = l >> 4;

    if (threadIdx.x < NFEAT)
        smask[threadIdx.x] = colmask[n * NFEAT + threadIdx.x];

    f64x4 zero = (f64x4){0.0, 0.0, 0.0, 0.0};
    f64x4 d1 = mfma_f64((double)lm, 1.0, zero);
    f64x4 d2 = mfma_f64(1.0, (double)lm, zero);
    int srow[4], pcol[4];
#pragma unroll
    for (int r = 0; r < 4; ++r) {
        int a = (int)(d1[r] * 0.25);
        int b = (int)(d2[r] * 0.25);
        srow[r] = (a < 0) ? 0 : (a > 15 ? 15 : a);
        pcol[r] = (b < 0) ? 0 : (b > 15 ? 15 : b);
    }
    __syncthreads();

    f64x4 acc[2][4];
    int pclamp[4];
#pragma unroll
    for (int i = 0; i < 4; ++i) {
        int p = chunk * 256 + (wv * 4 + i) * 16 + lm;
        pclamp[i] = (p < NP) ? p : (NP - 1);
        acc[0][i] = zero; acc[1][i] = zero;
    }
    for (int kt = 0; kt < 25; ++kt) {
        unsigned mw = smask[kt * 4 + lg];
        double a0 = ((mw >> lm) & 1u) ? 1.0 : 0.0;
        double a1 = ((mw >> (lm + 16)) & 1u) ? 1.0 : 0.0;
        const float* wrow = W2 + (size_t)(kt * 4 + lg) * NP;
#pragma unroll
        for (int i = 0; i < 4; ++i) {
            double b = (double)wrow[pclamp[i]];
            acc[0][i] = mfma_f64(a0, b, acc[0][i]);
            acc[1][i] = mfma_f64(a1, b, acc[1][i]);
        }
    }
#pragma unroll
    for (int hp = 0; hp < 2; ++hp) {
        __syncthreads();
        if ((wv >> 1) == hp) {
#pragma unroll
            for (int i = 0; i < 4; ++i) {
                int tloc = (wv & 1) * 4 + i;
#pragma unroll
                for (int st = 0; st < 2; ++st)
#pragma unroll
                    for (int r = 0; r < 4; ++r)
                        h_lds[st * 16 + srow[r]][tloc * 16 + pcol[r]] = acc[st][i][r];
            }
        }
        __syncthreads();
        if (threadIdx.x < 128) {
            int p = chunk * 256 + hp * 128 + threadIdx.x;
            if (p < NP) {
                double b2d = (double)B2[p];
                double mem = 0.0, spk = 0.0;
                int cnt = 0;
#pragma unroll
                for (int s = 0; s < NS; ++s) {
                    double h = h_lds[s][threadIdx.x] + b2d;
                    mem = 0.9 * mem + h - spk;
                    bool sp = mem > 1.0;
                    spk = sp ? 1.0 : 0.0;
                    cnt += sp;
                }
                out[(size_t)n * OUTC + NFEAT + p] = (float)((double)cnt / 30.0);
            }
        }
    }
}

// ---------------------------------------------------------------------------
extern "C" void kernel_launch(void* const* d_in, const int* in_sizes, int n_in,
                              void* d_out, int out_size, void* d_ws, size_t ws_size,
                              hipStream_t stream) {
    const float* X  = (const float*)d_in[0];
    const float* W1 = (const float*)d_in[1];
    const float* B1 = (const float*)d_in[2];
    const float* W2 = (const float*)d_in[3];
    const float* B2 = (const float*)d_in[4];
    const float* U  = (const float*)d_in[5];
    float* out = (float*)d_out;

    unsigned* colmask = (unsigned*)d_ws;                    // 819,200 B
    const size_t SLT_OFF = 1u << 20;                        // 1 MiB
    const size_t SLT_BYTES = (size_t)NWIN * NP * 128 * 2;   // 3,072,000 B
    unsigned short* slt = (unsigned short*)((char*)d_ws + SLT_OFF);
    bool use_bf16 = (ws_size >= SLT_OFF + SLT_BYTES);

    {
        int total = NN * NFEAT;
        sbls_k1<<<(total + 255) / 256, 256, 0, stream>>>(X, W1, B1, U, out, colmask);
    }
    if (use_bf16) {
        int total = NP * 128;
        sbls_slice<<<(total + 255) / 256, 256, 0, stream>>>(W2, slt);
        dim3 grid(NN / G, (NP + CHUNK - 1) / CHUNK);        // 512 x 32
        sbls_k2_bf16<<<grid, 256, 0, stream>>>(slt, B2, colmask, out);
    } else {
        dim3 grid(NN, (NP + 255) / 256);
        sbls_k2_f64<<<grid, 256, 0, stream>>>(W2, B2, colmask, out);
    }
}

// Round 9
// 432.095 us; speedup vs baseline: 1.7423x; 1.4631x over previous
//
#include <hip/hip_runtime.h>

// Problem dims (fixed by the reference)
#define NN      2048
#define IN_DIM  784
#define NFEAT   100
#define NP      2000   // MW*MP
#define NS      30
#define OUTC    2100   // NFEAT + NP
#define NWIN    6      // 8-bit windows covering bits 2^-4 .. 2^-51
#define G       4      // n-batch per block
#define CHUNK   64     // p per block

typedef double f64x4  __attribute__((ext_vector_type(4)));
typedef float  f32x4  __attribute__((ext_vector_type(4)));
typedef short  bf16x8 __attribute__((ext_vector_type(8)));

__device__ __forceinline__ f64x4 mfma_f64(double a, double b, f64x4 c) {
#if __has_builtin(__builtin_amdgcn_mfma_f64_16x16x4f64)
    return __builtin_amdgcn_mfma_f64_16x16x4f64(a, b, c, 0, 0, 0);
#else
    asm volatile("v_mfma_f64_16x16x4_f64 %0, %1, %2, %0"
                 : "+v"(c) : "v"(a), "v"(b));
    return c;
#endif
}

// ---------------------------------------------------------------------------
// Kernel 1: feature layer + Bernoulli rate coding (f64 decisions). Unchanged.
// ---------------------------------------------------------------------------
__global__ __launch_bounds__(256) void sbls_k1(
    const float* __restrict__ X, const float* __restrict__ W1,
    const float* __restrict__ B1, const float* __restrict__ U,
    float* __restrict__ out, unsigned* __restrict__ colmask)
{
    int tid = blockIdx.x * blockDim.x + threadIdx.x;
    if (tid >= NN * NFEAT) return;
    int n = tid / NFEAT;
    int f = tid - n * NFEAT;

    const float* xr = X + (size_t)n * IN_DIM;
    double acc = (double)B1[f];
    for (int k = 0; k < IN_DIM; ++k)
        acc += (double)xr[k] * (double)W1[k * NFEAT + f];

    double z = 1.0 / (1.0 + exp(-acc / 3.0));

    unsigned m = 0;
    int cnt = 0;
    for (int s = 0; s < NS; ++s) {
        float u = U[(size_t)s * (NN * NFEAT) + tid];
        int sp = ((double)u < z) ? 1 : 0;
        m |= (unsigned)sp << s;
        cnt += sp;
    }
    colmask[tid] = m;
    out[(size_t)n * OUTC + f] = (float)((double)cnt / 30.0);
}

// ---------------------------------------------------------------------------
// Slicer: W2 (f32, (NFEAT,NP)) -> 6 bf16 windows, transposed [w][p][f-pad128].
// Unchanged from the round-6-verified version (absmax 0.0).
// ---------------------------------------------------------------------------
__global__ __launch_bounds__(256) void sbls_slice(
    const float* __restrict__ W2, unsigned short* __restrict__ slt)
{
    int idx = blockIdx.x * blockDim.x + threadIdx.x;
    if (idx >= NP * 128) return;
    int f = idx & 127;
    int p = idx >> 7;

    double w = (f < NFEAT) ? (double)W2[(size_t)f * NP + p] : 0.0;
    double aw = fabs(w);
    double sg = (w < 0.0) ? -1.0 : 1.0;
    double r = aw;
    const double scale[NWIN] = {0x1p11, 0x1p19, 0x1p27, 0x1p35, 0x1p43, 0x1p51};
#pragma unroll
    for (int j = 0; j < NWIN; ++j) {
        double t = floor(r * scale[j]);          // integer in [0,255], exact
        r = r - t / scale[j];                     // exact (power-of-2 grid)
        float v = (float)(sg * t / scale[j]);     // <=8 sig bits -> exact
        unsigned u = __builtin_bit_cast(unsigned, v);
        slt[((size_t)j * NP + p) * 128 + f] = (unsigned short)(u >> 16);
    }
}

// ---------------------------------------------------------------------------
// Kernel 2 (v9): n-batched bf16 MFMA GEMM + fused LIF.
// Same structure as rounds 7/8 (G=4 n-batch, CHUNK=64, kt-outer, 8:1
// MFMA:B-load). FIX vs round 8: the epilogue n-loop is FULLY UNROLLED.
// Rounds 7/8 had "#pragma unroll 1" there, making acc[..][n] runtime-
// indexed -> entire acc array allocated in scratch (rule: runtime-indexed
// ext_vector arrays go to local memory) -> 0.8-2.4 GB/dispatch spill
// traffic, MfmaUtil 14%. With static indices acc stays in VGPR/AGPR.
// Numerics unchanged (absmax 0.0 proven in rounds 6-8).
// ---------------------------------------------------------------------------
__global__ __launch_bounds__(256, 2) void sbls_k2_bf16(
    const unsigned short* __restrict__ slt,  // [6][NP][128] bf16 slices
    const float*    __restrict__ B2,
    const unsigned* __restrict__ colmask,
    float*          __restrict__ out)
{
    __shared__ unsigned smask[G][NFEAT];
    __shared__ __align__(16) unsigned short afrag[32][64][8]; // 32 KB
    __shared__ double h_lds[32][CHUNK + 2];

    const int ng    = blockIdx.x;            // n-group (0..511)
    const int chunk = blockIdx.y;            // 0..31
    const int t  = threadIdx.x;
    const int l  = t & 63;
    const int wv = t >> 6;
    const int lm = l & 15;
    const int lg = l >> 4;

    for (int i = t; i < G * NFEAT; i += 256)
        smask[i / NFEAT][i % NFEAT] = colmask[(ng * G + i / NFEAT) * NFEAT + (i % NFEAT)];
    __syncthreads();

    // Build A-fragment table: fid = (kt*G + n)*2 + st, per-lane 8 bf16.
    // Element j of lane L: f = kt*32 + (L>>4)*8 + j ; bit s = st*16 + (L&15).
    for (int e = t; e < 32 * 64; e += 256) {
        int fid = e >> 6, L = e & 63;
        int st = fid & 1, n = (fid >> 1) & 3, kt = fid >> 3;
        int lgE = L >> 4, lmE = L & 15;
        int s = st * 16 + lmE;
        bf16x8 v;
#pragma unroll
        for (int j = 0; j < 8; ++j) {
            int f = kt * 32 + lgE * 8 + j;
            unsigned mv = (f < NFEAT) ? smask[n][f] : 0u;
            v[j] = (short)(((mv >> s) & 1u) ? 0x3F80 : 0);
        }
        *(bf16x8*)(&afrag[fid][L][0]) = v;
    }
    __syncthreads();

    const int p = chunk * CHUNK + wv * 16 + lm;
    const int prow = (p < NP) ? p : (NP - 1);
    const unsigned short* bbase = slt + (size_t)prow * 128 + lg * 8;

    f32x4 acc[3][2][G];
#pragma unroll
    for (int wp = 0; wp < 3; ++wp)
#pragma unroll
        for (int st = 0; st < 2; ++st)
#pragma unroll
            for (int n = 0; n < G; ++n)
                acc[wp][st][n] = (f32x4){0.f, 0.f, 0.f, 0.f};

#pragma unroll
    for (int kt = 0; kt < 4; ++kt) {
        bf16x8 a[G][2];
#pragma unroll
        for (int n = 0; n < G; ++n)
#pragma unroll
            for (int st = 0; st < 2; ++st)
                a[n][st] = *(const bf16x8*)(&afrag[(kt * G + n) * 2 + st][l][0]);
#pragma unroll
        for (int w = 0; w < 6; ++w) {
            const bf16x8 b = *(const bf16x8*)(bbase + (size_t)w * NP * 128 + kt * 32);
#pragma unroll
            for (int n = 0; n < G; ++n)
#pragma unroll
                for (int st = 0; st < 2; ++st)
                    acc[w >> 1][st][n] = __builtin_amdgcn_mfma_f32_16x16x32_bf16(
                        a[n][st], b, acc[w >> 1][st][n], 0, 0, 0);
        }
    }

    // Epilogue: per n (FULLY UNROLLED -> static acc indices), LDS transpose
    // + f64 LIF (round-5/6-verified path).
#pragma unroll
    for (int n = 0; n < G; ++n) {
        __syncthreads();
#pragma unroll
        for (int st = 0; st < 2; ++st)
#pragma unroll
            for (int r = 0; r < 4; ++r) {
                double hv = (double)acc[0][st][n][r]
                          + (double)acc[1][st][n][r]
                          + (double)acc[2][st][n][r];
                h_lds[st * 16 + lg * 4 + r][wv * 16 + lm] = hv;
            }
        __syncthreads();
        if (t < CHUNK) {
            int pp = chunk * CHUNK + t;
            if (pp < NP) {
                double b2d = (double)B2[pp];
                double mem = 0.0, spk = 0.0;
                int cnt = 0;
#pragma unroll
                for (int s = 0; s < NS; ++s) {
                    double h = h_lds[s][t] + b2d;
                    mem = 0.9 * mem + h - spk;
                    bool sp = mem > 1.0;
                    spk = sp ? 1.0 : 0.0;
                    cnt += sp;
                }
                out[(size_t)(ng * G + n) * OUTC + NFEAT + pp] = (float)((double)cnt / 30.0);
            }
        }
    }
}

// ---------------------------------------------------------------------------
// Fallback kernel 2 (round-5 f64 MFMA, probed layout) — used if ws too small.
// ---------------------------------------------------------------------------
__global__ __launch_bounds__(256, 2) void sbls_k2_f64(
    const float*    __restrict__ W2, const float* __restrict__ B2,
    const unsigned* __restrict__ colmask, float* __restrict__ out)
{
    __shared__ unsigned smask[NFEAT];
    __shared__ double h_lds[32][130];

    const int n     = blockIdx.x;
    const int chunk = blockIdx.y;
    const int l  = threadIdx.x & 63;
    const int wv = threadIdx.x >> 6;
    const int lm = l & 15;
    const int lg = l >> 4;

    if (threadIdx.x < NFEAT)
        smask[threadIdx.x] = colmask[n * NFEAT + threadIdx.x];

    f64x4 zero = (f64x4){0.0, 0.0, 0.0, 0.0};
    f64x4 d1 = mfma_f64((double)lm, 1.0, zero);
    f64x4 d2 = mfma_f64(1.0, (double)lm, zero);
    int srow[4], pcol[4];
#pragma unroll
    for (int r = 0; r < 4; ++r) {
        int a = (int)(d1[r] * 0.25);
        int b = (int)(d2[r] * 0.25);
        srow[r] = (a < 0) ? 0 : (a > 15 ? 15 : a);
        pcol[r] = (b < 0) ? 0 : (b > 15 ? 15 : b);
    }
    __syncthreads();

    f64x4 acc[2][4];
    int pclamp[4];
#pragma unroll
    for (int i = 0; i < 4; ++i) {
        int p = chunk * 256 + (wv * 4 + i) * 16 + lm;
        pclamp[i] = (p < NP) ? p : (NP - 1);
        acc[0][i] = zero; acc[1][i] = zero;
    }
    for (int kt = 0; kt < 25; ++kt) {
        unsigned mw = smask[kt * 4 + lg];
        double a0 = ((mw >> lm) & 1u) ? 1.0 : 0.0;
        double a1 = ((mw >> (lm + 16)) & 1u) ? 1.0 : 0.0;
        const float* wrow = W2 + (size_t)(kt * 4 + lg) * NP;
#pragma unroll
        for (int i = 0; i < 4; ++i) {
            double b = (double)wrow[pclamp[i]];
            acc[0][i] = mfma_f64(a0, b, acc[0][i]);
            acc[1][i] = mfma_f64(a1, b, acc[1][i]);
        }
    }
#pragma unroll
    for (int hp = 0; hp < 2; ++hp) {
        __syncthreads();
        if ((wv >> 1) == hp) {
#pragma unroll
            for (int i = 0; i < 4; ++i) {
                int tloc = (wv & 1) * 4 + i;
#pragma unroll
                for (int st = 0; st < 2; ++st)
#pragma unroll
                    for (int r = 0; r < 4; ++r)
                        h_lds[st * 16 + srow[r]][tloc * 16 + pcol[r]] = acc[st][i][r];
            }
        }
        __syncthreads();
        if (threadIdx.x < 128) {
            int p = chunk * 256 + hp * 128 + threadIdx.x;
            if (p < NP) {
                double b2d = (double)B2[p];
                double mem = 0.0, spk = 0.0;
                int cnt = 0;
#pragma unroll
                for (int s = 0; s < NS; ++s) {
                    double h = h_lds[s][threadIdx.x] + b2d;
                    mem = 0.9 * mem + h - spk;
                    bool sp = mem > 1.0;
                    spk = sp ? 1.0 : 0.0;
                    cnt += sp;
                }
                out[(size_t)n * OUTC + NFEAT + p] = (float)((double)cnt / 30.0);
            }
        }
    }
}

// ---------------------------------------------------------------------------
extern "C" void kernel_launch(void* const* d_in, const int* in_sizes, int n_in,
                              void* d_out, int out_size, void* d_ws, size_t ws_size,
                              hipStream_t stream) {
    const float* X  = (const float*)d_in[0];
    const float* W1 = (const float*)d_in[1];
    const float* B1 = (const float*)d_in[2];
    const float* W2 = (const float*)d_in[3];
    const float* B2 = (const float*)d_in[4];
    const float* U  = (const float*)d_in[5];
    float* out = (float*)d_out;

    unsigned* colmask = (unsigned*)d_ws;                    // 819,200 B
    const size_t SLT_OFF = 1u << 20;                        // 1 MiB
    const size_t SLT_BYTES = (size_t)NWIN * NP * 128 * 2;   // 3,072,000 B
    unsigned short* slt = (unsigned short*)((char*)d_ws + SLT_OFF);
    bool use_bf16 = (ws_size >= SLT_OFF + SLT_BYTES);

    {
        int total = NN * NFEAT;
        sbls_k1<<<(total + 255) / 256, 256, 0, stream>>>(X, W1, B1, U, out, colmask);
    }
    if (use_bf16) {
        int total = NP * 128;
        sbls_slice<<<(total + 255) / 256, 256, 0, stream>>>(W2, slt);
        dim3 grid(NN / G, (NP + CHUNK - 1) / CHUNK);        // 512 x 32
        sbls_k2_bf16<<<grid, 256, 0, stream>>>(slt, B2, colmask, out);
    } else {
        dim3 grid(NN, (NP + 255) / 256);
        sbls_k2_f64<<<grid, 256, 0, stream>>>(W2, B2, colmask, out);
    }
}

// Round 10
// 385.330 us; speedup vs baseline: 1.9538x; 1.1214x over previous
//
#include <hip/hip_runtime.h>

// Problem dims (fixed by the reference)
#define NN      2048
#define IN_DIM  784
#define NFEAT   100
#define NP      2000   // MW*MP
#define NS      30
#define OUTC    2100   // NFEAT + NP
#define NWIN    6      // 8-bit windows covering bits 2^-4 .. 2^-51
#define G       4      // n-batch per block
#define CHUNK   64     // p per block

typedef double f64x4  __attribute__((ext_vector_type(4)));
typedef float  f32x4  __attribute__((ext_vector_type(4)));
typedef short  bf16x8 __attribute__((ext_vector_type(8)));

__device__ __forceinline__ f64x4 mfma_f64(double a, double b, f64x4 c) {
#if __has_builtin(__builtin_amdgcn_mfma_f64_16x16x4f64)
    return __builtin_amdgcn_mfma_f64_16x16x4f64(a, b, c, 0, 0, 0);
#else
    asm volatile("v_mfma_f64_16x16x4_f64 %0, %1, %2, %0"
                 : "+v"(c) : "v"(a), "v"(b));
    return c;
#endif
}

// ---------------------------------------------------------------------------
// Kernel 1: feature layer + Bernoulli rate coding (f64 decisions). Unchanged.
// ---------------------------------------------------------------------------
__global__ __launch_bounds__(256) void sbls_k1(
    const float* __restrict__ X, const float* __restrict__ W1,
    const float* __restrict__ B1, const float* __restrict__ U,
    float* __restrict__ out, unsigned* __restrict__ colmask)
{
    int tid = blockIdx.x * blockDim.x + threadIdx.x;
    if (tid >= NN * NFEAT) return;
    int n = tid / NFEAT;
    int f = tid - n * NFEAT;

    const float* xr = X + (size_t)n * IN_DIM;
    double acc = (double)B1[f];
    for (int k = 0; k < IN_DIM; ++k)
        acc += (double)xr[k] * (double)W1[k * NFEAT + f];

    double z = 1.0 / (1.0 + exp(-acc / 3.0));

    unsigned m = 0;
    int cnt = 0;
    for (int s = 0; s < NS; ++s) {
        float u = U[(size_t)s * (NN * NFEAT) + tid];
        int sp = ((double)u < z) ? 1 : 0;
        m |= (unsigned)sp << s;
        cnt += sp;
    }
    colmask[tid] = m;
    out[(size_t)n * OUTC + f] = (float)((double)cnt / 30.0);
}

// ---------------------------------------------------------------------------
// Slicer: W2 (f32, (NFEAT,NP)) -> 6 bf16 windows, transposed [w][p][f-pad128].
// Unchanged from the round-6-verified version (absmax 0.0).
// ---------------------------------------------------------------------------
__global__ __launch_bounds__(256) void sbls_slice(
    const float* __restrict__ W2, unsigned short* __restrict__ slt)
{
    int idx = blockIdx.x * blockDim.x + threadIdx.x;
    if (idx >= NP * 128) return;
    int f = idx & 127;
    int p = idx >> 7;

    double w = (f < NFEAT) ? (double)W2[(size_t)f * NP + p] : 0.0;
    double aw = fabs(w);
    double sg = (w < 0.0) ? -1.0 : 1.0;
    double r = aw;
    const double scale[NWIN] = {0x1p11, 0x1p19, 0x1p27, 0x1p35, 0x1p43, 0x1p51};
#pragma unroll
    for (int j = 0; j < NWIN; ++j) {
        double t = floor(r * scale[j]);          // integer in [0,255], exact
        r = r - t / scale[j];                     // exact (power-of-2 grid)
        float v = (float)(sg * t / scale[j]);     // <=8 sig bits -> exact
        unsigned u = __builtin_bit_cast(unsigned, v);
        slt[((size_t)j * NP + p) * 128 + f] = (unsigned short)(u >> 16);
    }
}

// ---------------------------------------------------------------------------
// Kernel 2 (v10): n-batched bf16 MFMA GEMM + fused LIF.
// vs round 9: (1) afrag and h_lds share one LDS union (afrag is dead after
// the main loop) and (2) the epilogue handles n in PAIRS (h[2][32][66]),
// so LIF uses 128 threads x 2 passes instead of 64 x 4, with half the
// barriers. LDS 51.7 -> ~35.4 KB => 4 blocks/CU (was 2) for latency hiding.
// All indices into acc remain compile-time (epilogue fully unrolled) --
// rule #20. Numerics byte-identical (absmax 0.0 proven rounds 6-9).
// ---------------------------------------------------------------------------
union ShU {
    unsigned short afrag[32][64][8];   // 32 KB, fid = (kt*G+n)*2+st
    double h[2][32][66];               // 33.8 KB, [n-pair][s][p-local]
};

__global__ __launch_bounds__(256, 2) void sbls_k2_bf16(
    const unsigned short* __restrict__ slt,  // [6][NP][128] bf16 slices
    const float*    __restrict__ B2,
    const unsigned* __restrict__ colmask,
    float*          __restrict__ out)
{
    __shared__ unsigned smask[G][NFEAT];
    __shared__ __align__(16) ShU shu;

    const int ng    = blockIdx.x;            // n-group (0..511)
    const int chunk = blockIdx.y;            // 0..31
    const int t  = threadIdx.x;
    const int l  = t & 63;
    const int wv = t >> 6;
    const int lm = l & 15;
    const int lg = l >> 4;

    for (int i = t; i < G * NFEAT; i += 256)
        smask[i / NFEAT][i % NFEAT] = colmask[(ng * G + i / NFEAT) * NFEAT + (i % NFEAT)];
    __syncthreads();

    // Build A-fragment table: fid = (kt*G + n)*2 + st, per-lane 8 bf16.
    // Element j of lane L: f = kt*32 + (L>>4)*8 + j ; bit s = st*16 + (L&15).
    for (int e = t; e < 32 * 64; e += 256) {
        int fid = e >> 6, L = e & 63;
        int st = fid & 1, n = (fid >> 1) & 3, kt = fid >> 3;
        int lgE = L >> 4, lmE = L & 15;
        int s = st * 16 + lmE;
        bf16x8 v;
#pragma unroll
        for (int j = 0; j < 8; ++j) {
            int f = kt * 32 + lgE * 8 + j;
            unsigned mv = (f < NFEAT) ? smask[n][f] : 0u;
            v[j] = (short)(((mv >> s) & 1u) ? 0x3F80 : 0);
        }
        *(bf16x8*)(&shu.afrag[fid][L][0]) = v;
    }
    __syncthreads();

    const int p = chunk * CHUNK + wv * 16 + lm;
    const int prow = (p < NP) ? p : (NP - 1);
    const unsigned short* bbase = slt + (size_t)prow * 128 + lg * 8;

    f32x4 acc[3][2][G];
#pragma unroll
    for (int wp = 0; wp < 3; ++wp)
#pragma unroll
        for (int st = 0; st < 2; ++st)
#pragma unroll
            for (int n = 0; n < G; ++n)
                acc[wp][st][n] = (f32x4){0.f, 0.f, 0.f, 0.f};

#pragma unroll
    for (int kt = 0; kt < 4; ++kt) {
        bf16x8 a[G][2];
#pragma unroll
        for (int n = 0; n < G; ++n)
#pragma unroll
            for (int st = 0; st < 2; ++st)
                a[n][st] = *(const bf16x8*)(&shu.afrag[(kt * G + n) * 2 + st][l][0]);
#pragma unroll
        for (int w = 0; w < 6; ++w) {
            const bf16x8 b = *(const bf16x8*)(bbase + (size_t)w * NP * 128 + kt * 32);
#pragma unroll
            for (int n = 0; n < G; ++n)
#pragma unroll
                for (int st = 0; st < 2; ++st)
                    acc[w >> 1][st][n] = __builtin_amdgcn_mfma_f32_16x16x32_bf16(
                        a[n][st], b, acc[w >> 1][st][n], 0, 0, 0);
        }
    }

    // Epilogue: 2 passes, each covering an n-pair. Fully unrolled (static
    // acc indices). Pass: barrier (prev readers / afrag readers done) ->
    // write h[2][32][66] -> barrier -> 128-thread LIF.
#pragma unroll
    for (int np2 = 0; np2 < 2; ++np2) {
        __syncthreads();
#pragma unroll
        for (int nn = 0; nn < 2; ++nn) {
            const int n = np2 * 2 + nn;
#pragma unroll
            for (int st = 0; st < 2; ++st)
#pragma unroll
                for (int r = 0; r < 4; ++r) {
                    double hv = (double)acc[0][st][n][r]
                              + (double)acc[1][st][n][r]
                              + (double)acc[2][st][n][r];
                    shu.h[nn][st * 16 + lg * 4 + r][wv * 16 + lm] = hv;
                }
        }
        __syncthreads();
        if (t < 128) {
            int nn = t >> 6;
            int pl = t & 63;
            int pp = chunk * CHUNK + pl;
            if (pp < NP) {
                double b2d = (double)B2[pp];
                double mem = 0.0, spk = 0.0;
                int cnt = 0;
#pragma unroll
                for (int s = 0; s < NS; ++s) {
                    double h = shu.h[nn][s][pl] + b2d;
                    mem = 0.9 * mem + h - spk;
                    bool sp = mem > 1.0;
                    spk = sp ? 1.0 : 0.0;
                    cnt += sp;
                }
                out[(size_t)(ng * G + np2 * 2 + nn) * OUTC + NFEAT + pp] =
                    (float)((double)cnt / 30.0);
            }
        }
    }
}

// ---------------------------------------------------------------------------
// Fallback kernel 2 (round-5 f64 MFMA, probed layout) — used if ws too small.
// ---------------------------------------------------------------------------
__global__ __launch_bounds__(256, 2) void sbls_k2_f64(
    const float*    __restrict__ W2, const float* __restrict__ B2,
    const unsigned* __restrict__ colmask, float* __restrict__ out)
{
    __shared__ unsigned smask[NFEAT];
    __shared__ double h_lds[32][130];

    const int n     = blockIdx.x;
    const int chunk = blockIdx.y;
    const int l  = threadIdx.x & 63;
    const int wv = threadIdx.x >> 6;
    const int lm = l & 15;
    const int lg = l >> 4;

    if (threadIdx.x < NFEAT)
        smask[threadIdx.x] = colmask[n * NFEAT + threadIdx.x];

    f64x4 zero = (f64x4){0.0, 0.0, 0.0, 0.0};
    f64x4 d1 = mfma_f64((double)lm, 1.0, zero);
    f64x4 d2 = mfma_f64(1.0, (double)lm, zero);
    int srow[4], pcol[4];
#pragma unroll
    for (int r = 0; r < 4; ++r) {
        int a = (int)(d1[r] * 0.25);
        int b = (int)(d2[r] * 0.25);
        srow[r] = (a < 0) ? 0 : (a > 15 ? 15 : a);
        pcol[r] = (b < 0) ? 0 : (b > 15 ? 15 : b);
    }
    __syncthreads();

    f64x4 acc[2][4];
    int pclamp[4];
#pragma unroll
    for (int i = 0; i < 4; ++i) {
        int p = chunk * 256 + (wv * 4 + i) * 16 + lm;
        pclamp[i] = (p < NP) ? p : (NP - 1);
        acc[0][i] = zero; acc[1][i] = zero;
    }
    for (int kt = 0; kt < 25; ++kt) {
        unsigned mw = smask[kt * 4 + lg];
        double a0 = ((mw >> lm) & 1u) ? 1.0 : 0.0;
        double a1 = ((mw >> (lm + 16)) & 1u) ? 1.0 : 0.0;
        const float* wrow = W2 + (size_t)(kt * 4 + lg) * NP;
#pragma unroll
        for (int i = 0; i < 4; ++i) {
            double b = (double)wrow[pclamp[i]];
            acc[0][i] = mfma_f64(a0, b, acc[0][i]);
            acc[1][i] = mfma_f64(a1, b, acc[1][i]);
        }
    }
#pragma unroll
    for (int hp = 0; hp < 2; ++hp) {
        __syncthreads();
        if ((wv >> 1) == hp) {
#pragma unroll
            for (int i = 0; i < 4; ++i) {
                int tloc = (wv & 1) * 4 + i;
#pragma unroll
                for (int st = 0; st < 2; ++st)
#pragma unroll
                    for (int r = 0; r < 4; ++r)
                        h_lds[st * 16 + srow[r]][tloc * 16 + pcol[r]] = acc[st][i][r];
            }
        }
        __syncthreads();
        if (threadIdx.x < 128) {
            int p = chunk * 256 + hp * 128 + threadIdx.x;
            if (p < NP) {
                double b2d = (double)B2[p];
                double mem = 0.0, spk = 0.0;
                int cnt = 0;
#pragma unroll
                for (int s = 0; s < NS; ++s) {
                    double h = h_lds[s][threadIdx.x] + b2d;
                    mem = 0.9 * mem + h - spk;
                    bool sp = mem > 1.0;
                    spk = sp ? 1.0 : 0.0;
                    cnt += sp;
                }
                out[(size_t)n * OUTC + NFEAT + p] = (float)((double)cnt / 30.0);
            }
        }
    }
}

// ---------------------------------------------------------------------------
extern "C" void kernel_launch(void* const* d_in, const int* in_sizes, int n_in,
                              void* d_out, int out_size, void* d_ws, size_t ws_size,
                              hipStream_t stream) {
    const float* X  = (const float*)d_in[0];
    const float* W1 = (const float*)d_in[1];
    const float* B1 = (const float*)d_in[2];
    const float* W2 = (const float*)d_in[3];
    const float* B2 = (const float*)d_in[4];
    const float* U  = (const float*)d_in[5];
    float* out = (float*)d_out;

    unsigned* colmask = (unsigned*)d_ws;                    // 819,200 B
    const size_t SLT_OFF = 1u << 20;                        // 1 MiB
    const size_t SLT_BYTES = (size_t)NWIN * NP * 128 * 2;   // 3,072,000 B
    unsigned short* slt = (unsigned short*)((char*)d_ws + SLT_OFF);
    bool use_bf16 = (ws_size >= SLT_OFF + SLT_BYTES);

    {
        int total = NN * NFEAT;
        sbls_k1<<<(total + 255) / 256, 256, 0, stream>>>(X, W1, B1, U, out, colmask);
    }
    if (use_bf16) {
        int total = NP * 128;
        sbls_slice<<<(total + 255) / 256, 256, 0, stream>>>(W2, slt);
        dim3 grid(NN / G, (NP + CHUNK - 1) / CHUNK);        // 512 x 32
        sbls_k2_bf16<<<grid, 256, 0, stream>>>(slt, B2, colmask, out);
    } else {
        dim3 grid(NN, (NP + 255) / 256);
        sbls_k2_f64<<<grid, 256, 0, stream>>>(W2, B2, colmask, out);
    }
}

// Round 11
// 348.137 us; speedup vs baseline: 2.1625x; 1.1068x over previous
//
#include <hip/hip_runtime.h>

// Problem dims (fixed by the reference)
#define NN      2048
#define IN_DIM  784
#define NFEAT   100
#define NP      2000   // MW*MP
#define NS      30
#define OUTC    2100   // NFEAT + NP
#define NWIN    6      // 8-bit windows covering bits 2^-4 .. 2^-51
#define G       4      // n-batch per block
#define CHUNK   64     // p per block

typedef double f64x4  __attribute__((ext_vector_type(4)));
typedef float  f32x4  __attribute__((ext_vector_type(4)));
typedef short  bf16x8 __attribute__((ext_vector_type(8)));

__device__ __forceinline__ f64x4 mfma_f64(double a, double b, f64x4 c) {
#if __has_builtin(__builtin_amdgcn_mfma_f64_16x16x4f64)
    return __builtin_amdgcn_mfma_f64_16x16x4f64(a, b, c, 0, 0, 0);
#else
    asm volatile("v_mfma_f64_16x16x4_f64 %0, %1, %2, %0"
                 : "+v"(c) : "v"(a), "v"(b));
    return c;
#endif
}

// ---------------------------------------------------------------------------
// Kernel 1: feature layer + Bernoulli rate coding (f64 decisions). Unchanged.
// ---------------------------------------------------------------------------
__global__ __launch_bounds__(256) void sbls_k1(
    const float* __restrict__ X, const float* __restrict__ W1,
    const float* __restrict__ B1, const float* __restrict__ U,
    float* __restrict__ out, unsigned* __restrict__ colmask)
{
    int tid = blockIdx.x * blockDim.x + threadIdx.x;
    if (tid >= NN * NFEAT) return;
    int n = tid / NFEAT;
    int f = tid - n * NFEAT;

    const float* xr = X + (size_t)n * IN_DIM;
    double acc = (double)B1[f];
    for (int k = 0; k < IN_DIM; ++k)
        acc += (double)xr[k] * (double)W1[k * NFEAT + f];

    double z = 1.0 / (1.0 + exp(-acc / 3.0));

    unsigned m = 0;
    int cnt = 0;
    for (int s = 0; s < NS; ++s) {
        float u = U[(size_t)s * (NN * NFEAT) + tid];
        int sp = ((double)u < z) ? 1 : 0;
        m |= (unsigned)sp << s;
        cnt += sp;
    }
    colmask[tid] = m;
    out[(size_t)n * OUTC + f] = (float)((double)cnt / 30.0);
}

// ---------------------------------------------------------------------------
// Slicer: W2 (f32, (NFEAT,NP)) -> 6 bf16 windows, transposed [w][p][f-pad128].
// Unchanged from the round-6-verified version (absmax 0.0).
// ---------------------------------------------------------------------------
__global__ __launch_bounds__(256) void sbls_slice(
    const float* __restrict__ W2, unsigned short* __restrict__ slt)
{
    int idx = blockIdx.x * blockDim.x + threadIdx.x;
    if (idx >= NP * 128) return;
    int f = idx & 127;
    int p = idx >> 7;

    double w = (f < NFEAT) ? (double)W2[(size_t)f * NP + p] : 0.0;
    double aw = fabs(w);
    double sg = (w < 0.0) ? -1.0 : 1.0;
    double r = aw;
    const double scale[NWIN] = {0x1p11, 0x1p19, 0x1p27, 0x1p35, 0x1p43, 0x1p51};
#pragma unroll
    for (int j = 0; j < NWIN; ++j) {
        double t = floor(r * scale[j]);          // integer in [0,255], exact
        r = r - t / scale[j];                     // exact (power-of-2 grid)
        float v = (float)(sg * t / scale[j]);     // <=8 sig bits -> exact
        unsigned u = __builtin_bit_cast(unsigned, v);
        slt[((size_t)j * NP + p) * 128 + f] = (unsigned short)(u >> 16);
    }
}

// ---------------------------------------------------------------------------
// Kernel 2 (v11): n-batched bf16 MFMA GEMM + fused LIF.
// vs round 10:
//  (1) Explicit depth-1 software pipeline for the 6 B-loads: bnxt[] for
//      kt+1 issues BEFORE kt's 48-MFMA block (round 10 was load-latency
//      serialized: MfmaUtil 24.8% = exactly the MFMA floor). All indices
//      static (kt loop unrolled) -- rule #20 safe.
//  (2) Single-pass epilogue: h[4][32][67] (67-pad -> minimal 4-way b64
//      banking; 66 gave 8-way), union'd with afrag; all 256 threads run
//      LIF at once; one barrier pair instead of two.
// Numerics byte-identical (absmax 0.0 proven rounds 6-10).
// ---------------------------------------------------------------------------
union ShU {
    unsigned short afrag[32][64][8];   // 32 KB, fid = (kt*G+n)*2+st
    double h[G][32][67];               // 68.6 KB, [n][s][p-local]
};

__global__ __launch_bounds__(256, 2) void sbls_k2_bf16(
    const unsigned short* __restrict__ slt,  // [6][NP][128] bf16 slices
    const float*    __restrict__ B2,
    const unsigned* __restrict__ colmask,
    float*          __restrict__ out)
{
    __shared__ unsigned smask[G][NFEAT];
    __shared__ __align__(16) ShU shu;

    const int ng    = blockIdx.x;            // n-group (0..511)
    const int chunk = blockIdx.y;            // 0..31
    const int t  = threadIdx.x;
    const int l  = t & 63;
    const int wv = t >> 6;
    const int lm = l & 15;
    const int lg = l >> 4;

    for (int i = t; i < G * NFEAT; i += 256)
        smask[i / NFEAT][i % NFEAT] = colmask[(ng * G + i / NFEAT) * NFEAT + (i % NFEAT)];
    __syncthreads();

    // Build A-fragment table: fid = (kt*G + n)*2 + st, per-lane 8 bf16.
    // Element j of lane L: f = kt*32 + (L>>4)*8 + j ; bit s = st*16 + (L&15).
    for (int e = t; e < 32 * 64; e += 256) {
        int fid = e >> 6, L = e & 63;
        int st = fid & 1, n = (fid >> 1) & 3, kt = fid >> 3;
        int lgE = L >> 4, lmE = L & 15;
        int s = st * 16 + lmE;
        bf16x8 v;
#pragma unroll
        for (int j = 0; j < 8; ++j) {
            int f = kt * 32 + lgE * 8 + j;
            unsigned mv = (f < NFEAT) ? smask[n][f] : 0u;
            v[j] = (short)(((mv >> s) & 1u) ? 0x3F80 : 0);
        }
        *(bf16x8*)(&shu.afrag[fid][L][0]) = v;
    }
    __syncthreads();

    const int p = chunk * CHUNK + wv * 16 + lm;
    const int prow = (p < NP) ? p : (NP - 1);
    const unsigned short* bbase = slt + (size_t)prow * 128 + lg * 8;

    f32x4 acc[3][2][G];
#pragma unroll
    for (int wp = 0; wp < 3; ++wp)
#pragma unroll
        for (int st = 0; st < 2; ++st)
#pragma unroll
            for (int n = 0; n < G; ++n)
                acc[wp][st][n] = (f32x4){0.f, 0.f, 0.f, 0.f};

    // Depth-1 pipelined main loop: kt+1's B in flight under kt's MFMAs.
    bf16x8 bcur[6], bnxt[6];
#pragma unroll
    for (int w = 0; w < 6; ++w)
        bcur[w] = *(const bf16x8*)(bbase + (size_t)w * NP * 128);

#pragma unroll
    for (int kt = 0; kt < 4; ++kt) {
        bf16x8 a[G][2];
#pragma unroll
        for (int n = 0; n < G; ++n)
#pragma unroll
            for (int st = 0; st < 2; ++st)
                a[n][st] = *(const bf16x8*)(&shu.afrag[(kt * G + n) * 2 + st][l][0]);

        if (kt < 3) {
#pragma unroll
            for (int w = 0; w < 6; ++w)
                bnxt[w] = *(const bf16x8*)(bbase + (size_t)w * NP * 128 + (kt + 1) * 32);
        }

#pragma unroll
        for (int w = 0; w < 6; ++w) {
#pragma unroll
            for (int n = 0; n < G; ++n)
#pragma unroll
                for (int st = 0; st < 2; ++st)
                    acc[w >> 1][st][n] = __builtin_amdgcn_mfma_f32_16x16x32_bf16(
                        a[n][st], bcur[w], acc[w >> 1][st][n], 0, 0, 0);
        }

        if (kt < 3) {
#pragma unroll
            for (int w = 0; w < 6; ++w) bcur[w] = bnxt[w];
        }
    }

    // Single-pass epilogue: write all G n's h, one barrier pair, 256-thread
    // LIF (nn = t>>6). All acc indices compile-time (rule #20).
    __syncthreads();   // main-loop afrag readers done
#pragma unroll
    for (int n = 0; n < G; ++n)
#pragma unroll
        for (int st = 0; st < 2; ++st)
#pragma unroll
            for (int r = 0; r < 4; ++r) {
                double hv = (double)acc[0][st][n][r]
                          + (double)acc[1][st][n][r]
                          + (double)acc[2][st][n][r];
                shu.h[n][st * 16 + lg * 4 + r][wv * 16 + lm] = hv;
            }
    __syncthreads();
    {
        const int nn = t >> 6;     // 0..3
        const int pl = t & 63;     // 0..63
        const int pp = chunk * CHUNK + pl;
        if (pp < NP) {
            double b2d = (double)B2[pp];
            double mem = 0.0, spk = 0.0;
            int cnt = 0;
#pragma unroll
            for (int s = 0; s < NS; ++s) {
                double h = shu.h[nn][s][pl] + b2d;
                mem = 0.9 * mem + h - spk;
                bool sp = mem > 1.0;
                spk = sp ? 1.0 : 0.0;
                cnt += sp;
            }
            out[(size_t)(ng * G + nn) * OUTC + NFEAT + pp] = (float)((double)cnt / 30.0);
        }
    }
}

// ---------------------------------------------------------------------------
// Fallback kernel 2 (round-5 f64 MFMA, probed layout) — used if ws too small.
// ---------------------------------------------------------------------------
__global__ __launch_bounds__(256, 2) void sbls_k2_f64(
    const float*    __restrict__ W2, const float* __restrict__ B2,
    const unsigned* __restrict__ colmask, float* __restrict__ out)
{
    __shared__ unsigned smask[NFEAT];
    __shared__ double h_lds[32][130];

    const int n     = blockIdx.x;
    const int chunk = blockIdx.y;
    const int l  = threadIdx.x & 63;
    const int wv = threadIdx.x >> 6;
    const int lm = l & 15;
    const int lg = l >> 4;

    if (threadIdx.x < NFEAT)
        smask[threadIdx.x] = colmask[n * NFEAT + threadIdx.x];

    f64x4 zero = (f64x4){0.0, 0.0, 0.0, 0.0};
    f64x4 d1 = mfma_f64((double)lm, 1.0, zero);
    f64x4 d2 = mfma_f64(1.0, (double)lm, zero);
    int srow[4], pcol[4];
#pragma unroll
    for (int r = 0; r < 4; ++r) {
        int a = (int)(d1[r] * 0.25);
        int b = (int)(d2[r] * 0.25);
        srow[r] = (a < 0) ? 0 : (a > 15 ? 15 : a);
        pcol[r] = (b < 0) ? 0 : (b > 15 ? 15 : b);
    }
    __syncthreads();

    f64x4 acc[2][4];
    int pclamp[4];
#pragma unroll
    for (int i = 0; i < 4; ++i) {
        int p = chunk * 256 + (wv * 4 + i) * 16 + lm;
        pclamp[i] = (p < NP) ? p : (NP - 1);
        acc[0][i] = zero; acc[1][i] = zero;
    }
    for (int kt = 0; kt < 25; ++kt) {
        unsigned mw = smask[kt * 4 + lg];
        double a0 = ((mw >> lm) & 1u) ? 1.0 : 0.0;
        double a1 = ((mw >> (lm + 16)) & 1u) ? 1.0 : 0.0;
        const float* wrow = W2 + (size_t)(kt * 4 + lg) * NP;
#pragma unroll
        for (int i = 0; i < 4; ++i) {
            double b = (double)wrow[pclamp[i]];
            acc[0][i] = mfma_f64(a0, b, acc[0][i]);
            acc[1][i] = mfma_f64(a1, b, acc[1][i]);
        }
    }
#pragma unroll
    for (int hp = 0; hp < 2; ++hp) {
        __syncthreads();
        if ((wv >> 1) == hp) {
#pragma unroll
            for (int i = 0; i < 4; ++i) {
                int tloc = (wv & 1) * 4 + i;
#pragma unroll
                for (int st = 0; st < 2; ++st)
#pragma unroll
                    for (int r = 0; r < 4; ++r)
                        h_lds[st * 16 + srow[r]][tloc * 16 + pcol[r]] = acc[st][i][r];
            }
        }
        __syncthreads();
        if (threadIdx.x < 128) {
            int p = chunk * 256 + hp * 128 + threadIdx.x;
            if (p < NP) {
                double b2d = (double)B2[p];
                double mem = 0.0, spk = 0.0;
                int cnt = 0;
#pragma unroll
                for (int s = 0; s < NS; ++s) {
                    double h = h_lds[s][threadIdx.x] + b2d;
                    mem = 0.9 * mem + h - spk;
                    bool sp = mem > 1.0;
                    spk = sp ? 1.0 : 0.0;
                    cnt += sp;
                }
                out[(size_t)n * OUTC + NFEAT + p] = (float)((double)cnt / 30.0);
            }
        }
    }
}

// ---------------------------------------------------------------------------
extern "C" void kernel_launch(void* const* d_in, const int* in_sizes, int n_in,
                              void* d_out, int out_size, void* d_ws, size_t ws_size,
                              hipStream_t stream) {
    const float* X  = (const float*)d_in[0];
    const float* W1 = (const float*)d_in[1];
    const float* B1 = (const float*)d_in[2];
    const float* W2 = (const float*)d_in[3];
    const float* B2 = (const float*)d_in[4];
    const float* U  = (const float*)d_in[5];
    float* out = (float*)d_out;

    unsigned* colmask = (unsigned*)d_ws;                    // 819,200 B
    const size_t SLT_OFF = 1u << 20;                        // 1 MiB
    const size_t SLT_BYTES = (size_t)NWIN * NP * 128 * 2;   // 3,072,000 B
    unsigned short* slt = (unsigned short*)((char*)d_ws + SLT_OFF);
    bool use_bf16 = (ws_size >= SLT_OFF + SLT_BYTES);

    {
        int total = NN * NFEAT;
        sbls_k1<<<(total + 255) / 256, 256, 0, stream>>>(X, W1, B1, U, out, colmask);
    }
    if (use_bf16) {
        int total = NP * 128;
        sbls_slice<<<(total + 255) / 256, 256, 0, stream>>>(W2, slt);
        dim3 grid(NN / G, (NP + CHUNK - 1) / CHUNK);        // 512 x 32
        sbls_k2_bf16<<<grid, 256, 0, stream>>>(slt, B2, colmask, out);
    } else {
        dim3 grid(NN, (NP + 255) / 256);
        sbls_k2_f64<<<grid, 256, 0, stream>>>(W2, B2, colmask, out);
    }
}

// Round 12
// 290.021 us; speedup vs baseline: 2.5958x; 1.2004x over previous
//
#include <hip/hip_runtime.h>

// Problem dims (fixed by the reference)
#define NN      2048
#define IN_DIM  784
#define NFEAT   100
#define NP      2000   // MW*MP
#define NS      30
#define OUTC    2100   // NFEAT + NP
#define NWIN    5      // 8-bit windows covering bits 2^-4 .. 2^-43
#define G       4      // n-batch per block
#define CHUNK   64     // p per block

typedef double f64x4  __attribute__((ext_vector_type(4)));
typedef float  f32x4  __attribute__((ext_vector_type(4)));
typedef short  bf16x8 __attribute__((ext_vector_type(8)));

__device__ __forceinline__ f64x4 mfma_f64(double a, double b, f64x4 c) {
#if __has_builtin(__builtin_amdgcn_mfma_f64_16x16x4f64)
    return __builtin_amdgcn_mfma_f64_16x16x4f64(a, b, c, 0, 0, 0);
#else
    asm volatile("v_mfma_f64_16x16x4_f64 %0, %1, %2, %0"
                 : "+v"(c) : "v"(a), "v"(b));
    return c;
#endif
}

// ---------------------------------------------------------------------------
// Kernel 1 (v12): block-per-n feature layer + Bernoulli rate coding.
// X row staged in LDS (coalesced); W1/U reads coalesced over f; 4-way ILP
// f64 dot. f64 summation-order changes vs numpy are safe: slop ~1e-16 vs
// sigmoid decision margins (flip prob ~1e-9 across all 6.1M decisions).
// ---------------------------------------------------------------------------
__global__ __launch_bounds__(128) void sbls_k1(
    const float* __restrict__ X, const float* __restrict__ W1,
    const float* __restrict__ B1, const float* __restrict__ U,
    float* __restrict__ out, unsigned* __restrict__ colmask)
{
    __shared__ float xs[IN_DIM];
    const int n = blockIdx.x;
    const int t = threadIdx.x;

    for (int k = t; k < IN_DIM; k += 128)
        xs[k] = X[(size_t)n * IN_DIM + k];
    __syncthreads();

    if (t >= NFEAT) return;
    const int f = t;

    double a0 = 0.0, a1 = 0.0, a2 = 0.0, a3 = 0.0;
    for (int k = 0; k < IN_DIM; k += 4) {   // 784 = 4*196 exact
        a0 += (double)xs[k + 0] * (double)W1[(k + 0) * NFEAT + f];
        a1 += (double)xs[k + 1] * (double)W1[(k + 1) * NFEAT + f];
        a2 += (double)xs[k + 2] * (double)W1[(k + 2) * NFEAT + f];
        a3 += (double)xs[k + 3] * (double)W1[(k + 3) * NFEAT + f];
    }
    double acc = (double)B1[f] + ((a0 + a1) + (a2 + a3));
    double z = 1.0 / (1.0 + exp(-acc / 3.0));

    unsigned m = 0;
    int cnt = 0;
    for (int s = 0; s < NS; ++s) {
        float u = U[(size_t)s * (NN * NFEAT) + (size_t)n * NFEAT + f];
        int sp = ((double)u < z) ? 1 : 0;
        m |= (unsigned)sp << s;
        cnt += sp;
    }
    colmask[n * NFEAT + f] = m;
    out[(size_t)n * OUTC + f] = (float)((double)cnt / 30.0);
}

// ---------------------------------------------------------------------------
// Slicer: W2 (f32, (NFEAT,NP)) -> NWIN bf16 windows, transposed
// [w][p][f-pad128]. Same exact construction as rounds 6-11 (absmax 0.0),
// truncation now < 2^-43 (NWIN=5) -- error budget analyzed: expected LIF
// decision flips ~1e-3 (vs 1 flip = fail).
// ---------------------------------------------------------------------------
__global__ __launch_bounds__(256) void sbls_slice(
    const float* __restrict__ W2, unsigned short* __restrict__ slt)
{
    int idx = blockIdx.x * blockDim.x + threadIdx.x;
    if (idx >= NP * 128) return;
    int f = idx & 127;
    int p = idx >> 7;

    double w = (f < NFEAT) ? (double)W2[(size_t)f * NP + p] : 0.0;
    double aw = fabs(w);
    double sg = (w < 0.0) ? -1.0 : 1.0;
    double r = aw;
    const double scale[NWIN] = {0x1p11, 0x1p19, 0x1p27, 0x1p35, 0x1p43};
#pragma unroll
    for (int j = 0; j < NWIN; ++j) {
        double t = floor(r * scale[j]);          // integer in [0,255], exact
        r = r - t / scale[j];                     // exact (power-of-2 grid)
        float v = (float)(sg * t / scale[j]);     // <=8 sig bits -> exact
        unsigned u = __builtin_bit_cast(unsigned, v);
        slt[((size_t)j * NP + p) * 128 + f] = (unsigned short)(u >> 16);
    }
}

// ---------------------------------------------------------------------------
// k1b: build ALL A-fragment tables to global (one block per n-group).
// Layout: afragG[(ng*2048 + fid*64 + L) * 8] bf16, fid=(kt*G+n)*2+st.
// Removes the per-(ng,chunk) redundant build (was rebuilt 32x) from k2.
// ---------------------------------------------------------------------------
__global__ __launch_bounds__(256) void sbls_afrag(
    const unsigned* __restrict__ colmask, unsigned short* __restrict__ afragG)
{
    __shared__ unsigned smask[G][NFEAT];
    const int ng = blockIdx.x;
    const int t  = threadIdx.x;

    for (int i = t; i < G * NFEAT; i += 256)
        smask[i / NFEAT][i % NFEAT] = colmask[ng * G * NFEAT + i];
    __syncthreads();

    for (int e = t; e < 32 * 64; e += 256) {
        int fid = e >> 6, L = e & 63;
        int st = fid & 1, n = (fid >> 1) & 3, kt = fid >> 3;
        int lgE = L >> 4, lmE = L & 15;
        int s = st * 16 + lmE;
        bf16x8 v;
#pragma unroll
        for (int j = 0; j < 8; ++j) {
            int f = kt * 32 + lgE * 8 + j;
            unsigned mv = (f < NFEAT) ? smask[n][f] : 0u;
            v[j] = (short)(((mv >> s) & 1u) ? 0x3F80 : 0);
        }
        *(bf16x8*)(afragG + ((size_t)ng * 2048 + e) * 8) = v;
    }
}

// ---------------------------------------------------------------------------
// Kernel 2 (v12, tier A): barrier-free main loop. A-fragments and B slices
// both come from global (L2-resident, afrag reused 32x across chunks), so
// the compiler can pipeline loads freely across the whole unrolled K loop.
// Single barrier per block (epilogue h handoff). Numerics: identical
// integer-exact window-pair construction (absmax 0.0, rounds 6-11).
// ---------------------------------------------------------------------------
__global__ __launch_bounds__(256, 2) void sbls_k2_ga(
    const unsigned short* __restrict__ slt,     // [NWIN][NP][128]
    const unsigned short* __restrict__ afragG,  // [512][32][64][8]
    const float*    __restrict__ B2,
    float*          __restrict__ out)
{
    __shared__ double h[G][32][67];   // 68.6 KB

    const int ng    = blockIdx.x;            // 0..511
    const int chunk = blockIdx.y;            // 0..31
    const int t  = threadIdx.x;
    const int l  = t & 63;
    const int wv = t >> 6;
    const int lm = l & 15;
    const int lg = l >> 4;

    const int p = chunk * CHUNK + wv * 16 + lm;
    const int prow = (p < NP) ? p : (NP - 1);
    const unsigned short* bbase = slt + (size_t)prow * 128 + lg * 8;
    const unsigned short* ag = afragG + (size_t)ng * 2048 * 8;

    f32x4 acc[3][2][G];
#pragma unroll
    for (int wp = 0; wp < 3; ++wp)
#pragma unroll
        for (int st = 0; st < 2; ++st)
#pragma unroll
            for (int n = 0; n < G; ++n)
                acc[wp][st][n] = (f32x4){0.f, 0.f, 0.f, 0.f};

    bf16x8 bcur[NWIN], bnxt[NWIN];
#pragma unroll
    for (int w = 0; w < NWIN; ++w)
        bcur[w] = *(const bf16x8*)(bbase + (size_t)w * NP * 128);

#pragma unroll
    for (int kt = 0; kt < 4; ++kt) {
        bf16x8 a[G][2];
#pragma unroll
        for (int n = 0; n < G; ++n)
#pragma unroll
            for (int st = 0; st < 2; ++st)
                a[n][st] = *(const bf16x8*)(
                    ag + ((size_t)(((kt * G + n) * 2 + st) * 64 + l)) * 8);

        if (kt < 3) {
#pragma unroll
            for (int w = 0; w < NWIN; ++w)
                bnxt[w] = *(const bf16x8*)(bbase + (size_t)w * NP * 128 + (kt + 1) * 32);
        }

#pragma unroll
        for (int w = 0; w < NWIN; ++w) {
#pragma unroll
            for (int n = 0; n < G; ++n)
#pragma unroll
                for (int st = 0; st < 2; ++st)
                    acc[w >> 1][st][n] = __builtin_amdgcn_mfma_f32_16x16x32_bf16(
                        a[n][st], bcur[w], acc[w >> 1][st][n], 0, 0, 0);
        }

        if (kt < 3) {
#pragma unroll
            for (int w = 0; w < NWIN; ++w) bcur[w] = bnxt[w];
        }
    }

    // Epilogue: write h (disjoint slots), ONE barrier, 256-thread f64 LIF.
#pragma unroll
    for (int n = 0; n < G; ++n)
#pragma unroll
        for (int st = 0; st < 2; ++st)
#pragma unroll
            for (int r = 0; r < 4; ++r) {
                double hv = (double)acc[0][st][n][r]
                          + (double)acc[1][st][n][r]
                          + (double)acc[2][st][n][r];
                h[n][st * 16 + lg * 4 + r][wv * 16 + lm] = hv;
            }
    __syncthreads();
    {
        const int nn = t >> 6;     // 0..3
        const int pl = t & 63;     // 0..63
        const int pp = chunk * CHUNK + pl;
        if (pp < NP) {
            double b2d = (double)B2[pp];
            double mem = 0.0, spk = 0.0;
            int cnt = 0;
#pragma unroll
            for (int s = 0; s < NS; ++s) {
                double hh = h[nn][s][pl] + b2d;
                mem = 0.9 * mem + hh - spk;
                bool sp = mem > 1.0;
                spk = sp ? 1.0 : 0.0;
                cnt += sp;
            }
            out[(size_t)(ng * G + nn) * OUTC + NFEAT + pp] = (float)((double)cnt / 30.0);
        }
    }
}

// ---------------------------------------------------------------------------
// Tier B fallback (round-11 structure, NWIN=5): LDS-built afrag, pipelined.
// ---------------------------------------------------------------------------
union ShU {
    unsigned short afrag[32][64][8];   // 32 KB
    double h[G][32][67];               // 68.6 KB
};

__global__ __launch_bounds__(256, 2) void sbls_k2_bf16(
    const unsigned short* __restrict__ slt,
    const float*    __restrict__ B2,
    const unsigned* __restrict__ colmask,
    float*          __restrict__ out)
{
    __shared__ unsigned smask[G][NFEAT];
    __shared__ __align__(16) ShU shu;

    const int ng    = blockIdx.x;
    const int chunk = blockIdx.y;
    const int t  = threadIdx.x;
    const int l  = t & 63;
    const int wv = t >> 6;
    const int lm = l & 15;
    const int lg = l >> 4;

    for (int i = t; i < G * NFEAT; i += 256)
        smask[i / NFEAT][i % NFEAT] = colmask[(ng * G + i / NFEAT) * NFEAT + (i % NFEAT)];
    __syncthreads();

    for (int e = t; e < 32 * 64; e += 256) {
        int fid = e >> 6, L = e & 63;
        int st = fid & 1, n = (fid >> 1) & 3, kt = fid >> 3;
        int lgE = L >> 4, lmE = L & 15;
        int s = st * 16 + lmE;
        bf16x8 v;
#pragma unroll
        for (int j = 0; j < 8; ++j) {
            int f = kt * 32 + lgE * 8 + j;
            unsigned mv = (f < NFEAT) ? smask[n][f] : 0u;
            v[j] = (short)(((mv >> s) & 1u) ? 0x3F80 : 0);
        }
        *(bf16x8*)(&shu.afrag[fid][L][0]) = v;
    }
    __syncthreads();

    const int p = chunk * CHUNK + wv * 16 + lm;
    const int prow = (p < NP) ? p : (NP - 1);
    const unsigned short* bbase = slt + (size_t)prow * 128 + lg * 8;

    f32x4 acc[3][2][G];
#pragma unroll
    for (int wp = 0; wp < 3; ++wp)
#pragma unroll
        for (int st = 0; st < 2; ++st)
#pragma unroll
            for (int n = 0; n < G; ++n)
                acc[wp][st][n] = (f32x4){0.f, 0.f, 0.f, 0.f};

    bf16x8 bcur[NWIN], bnxt[NWIN];
#pragma unroll
    for (int w = 0; w < NWIN; ++w)
        bcur[w] = *(const bf16x8*)(bbase + (size_t)w * NP * 128);

#pragma unroll
    for (int kt = 0; kt < 4; ++kt) {
        bf16x8 a[G][2];
#pragma unroll
        for (int n = 0; n < G; ++n)
#pragma unroll
            for (int st = 0; st < 2; ++st)
                a[n][st] = *(const bf16x8*)(&shu.afrag[(kt * G + n) * 2 + st][l][0]);

        if (kt < 3) {
#pragma unroll
            for (int w = 0; w < NWIN; ++w)
                bnxt[w] = *(const bf16x8*)(bbase + (size_t)w * NP * 128 + (kt + 1) * 32);
        }

#pragma unroll
        for (int w = 0; w < NWIN; ++w) {
#pragma unroll
            for (int n = 0; n < G; ++n)
#pragma unroll
                for (int st = 0; st < 2; ++st)
                    acc[w >> 1][st][n] = __builtin_amdgcn_mfma_f32_16x16x32_bf16(
                        a[n][st], bcur[w], acc[w >> 1][st][n], 0, 0, 0);
        }

        if (kt < 3) {
#pragma unroll
            for (int w = 0; w < NWIN; ++w) bcur[w] = bnxt[w];
        }
    }

    __syncthreads();
#pragma unroll
    for (int n = 0; n < G; ++n)
#pragma unroll
        for (int st = 0; st < 2; ++st)
#pragma unroll
            for (int r = 0; r < 4; ++r) {
                double hv = (double)acc[0][st][n][r]
                          + (double)acc[1][st][n][r]
                          + (double)acc[2][st][n][r];
                shu.h[n][st * 16 + lg * 4 + r][wv * 16 + lm] = hv;
            }
    __syncthreads();
    {
        const int nn = t >> 6;
        const int pl = t & 63;
        const int pp = chunk * CHUNK + pl;
        if (pp < NP) {
            double b2d = (double)B2[pp];
            double mem = 0.0, spk = 0.0;
            int cnt = 0;
#pragma unroll
            for (int s = 0; s < NS; ++s) {
                double hh = shu.h[nn][s][pl] + b2d;
                mem = 0.9 * mem + hh - spk;
                bool sp = mem > 1.0;
                spk = sp ? 1.0 : 0.0;
                cnt += sp;
            }
            out[(size_t)(ng * G + nn) * OUTC + NFEAT + pp] = (float)((double)cnt / 30.0);
        }
    }
}

// ---------------------------------------------------------------------------
// Tier C fallback (round-5 f64 MFMA, probed layout).
// ---------------------------------------------------------------------------
__global__ __launch_bounds__(256, 2) void sbls_k2_f64(
    const float*    __restrict__ W2, const float* __restrict__ B2,
    const unsigned* __restrict__ colmask, float* __restrict__ out)
{
    __shared__ unsigned smask[NFEAT];
    __shared__ double h_lds[32][130];

    const int n     = blockIdx.x;
    const int chunk = blockIdx.y;
    const int l  = threadIdx.x & 63;
    const int wv = threadIdx.x >> 6;
    const int lm = l & 15;
    const int lg = l >> 4;

    if (threadIdx.x < NFEAT)
        smask[threadIdx.x] = colmask[n * NFEAT + threadIdx.x];

    f64x4 zero = (f64x4){0.0, 0.0, 0.0, 0.0};
    f64x4 d1 = mfma_f64((double)lm, 1.0, zero);
    f64x4 d2 = mfma_f64(1.0, (double)lm, zero);
    int srow[4], pcol[4];
#pragma unroll
    for (int r = 0; r < 4; ++r) {
        int a = (int)(d1[r] * 0.25);
        int b = (int)(d2[r] * 0.25);
        srow[r] = (a < 0) ? 0 : (a > 15 ? 15 : a);
        pcol[r] = (b < 0) ? 0 : (b > 15 ? 15 : b);
    }
    __syncthreads();

    f64x4 acc[2][4];
    int pclamp[4];
#pragma unroll
    for (int i = 0; i < 4; ++i) {
        int p = chunk * 256 + (wv * 4 + i) * 16 + lm;
        pclamp[i] = (p < NP) ? p : (NP - 1);
        acc[0][i] = zero; acc[1][i] = zero;
    }
    for (int kt = 0; kt < 25; ++kt) {
        unsigned mw = smask[kt * 4 + lg];
        double a0 = ((mw >> lm) & 1u) ? 1.0 : 0.0;
        double a1 = ((mw >> (lm + 16)) & 1u) ? 1.0 : 0.0;
        const float* wrow = W2 + (size_t)(kt * 4 + lg) * NP;
#pragma unroll
        for (int i = 0; i < 4; ++i) {
            double b = (double)wrow[pclamp[i]];
            acc[0][i] = mfma_f64(a0, b, acc[0][i]);
            acc[1][i] = mfma_f64(a1, b, acc[1][i]);
        }
    }
#pragma unroll
    for (int hp = 0; hp < 2; ++hp) {
        __syncthreads();
        if ((wv >> 1) == hp) {
#pragma unroll
            for (int i = 0; i < 4; ++i) {
                int tloc = (wv & 1) * 4 + i;
#pragma unroll
                for (int st = 0; st < 2; ++st)
#pragma unroll
                    for (int r = 0; r < 4; ++r)
                        h_lds[st * 16 + srow[r]][tloc * 16 + pcol[r]] = acc[st][i][r];
            }
        }
        __syncthreads();
        if (threadIdx.x < 128) {
            int p = chunk * 256 + hp * 128 + threadIdx.x;
            if (p < NP) {
                double b2d = (double)B2[p];
                double mem = 0.0, spk = 0.0;
                int cnt = 0;
#pragma unroll
                for (int s = 0; s < NS; ++s) {
                    double hh = h_lds[s][threadIdx.x] + b2d;
                    mem = 0.9 * mem + hh - spk;
                    bool sp = mem > 1.0;
                    spk = sp ? 1.0 : 0.0;
                    cnt += sp;
                }
                out[(size_t)n * OUTC + NFEAT + p] = (float)((double)cnt / 30.0);
            }
        }
    }
}

// ---------------------------------------------------------------------------
extern "C" void kernel_launch(void* const* d_in, const int* in_sizes, int n_in,
                              void* d_out, int out_size, void* d_ws, size_t ws_size,
                              hipStream_t stream) {
    const float* X  = (const float*)d_in[0];
    const float* W1 = (const float*)d_in[1];
    const float* B1 = (const float*)d_in[2];
    const float* W2 = (const float*)d_in[3];
    const float* B2 = (const float*)d_in[4];
    const float* U  = (const float*)d_in[5];
    float* out = (float*)d_out;

    unsigned* colmask = (unsigned*)d_ws;                      // 819,200 B
    const size_t SLT_OFF   = 1u << 20;                        // 1 MiB
    const size_t SLT_BYTES = (size_t)NWIN * NP * 128 * 2;     // 2,560,000 B
    const size_t AF_OFF    = 4u << 20;                        // 4 MiB
    const size_t AF_BYTES  = (size_t)512 * 2048 * 8 * 2;      // 16,777,216 B
    unsigned short* slt    = (unsigned short*)((char*)d_ws + SLT_OFF);
    unsigned short* afragG = (unsigned short*)((char*)d_ws + AF_OFF);
    bool tierA = (ws_size >= AF_OFF + AF_BYTES);
    bool tierB = (ws_size >= SLT_OFF + SLT_BYTES);

    sbls_k1<<<NN, 128, 0, stream>>>(X, W1, B1, U, out, colmask);

    if (tierA) {
        sbls_slice<<<(NP * 128 + 255) / 256, 256, 0, stream>>>(W2, slt);
        sbls_afrag<<<NN / G, 256, 0, stream>>>(colmask, afragG);
        dim3 grid(NN / G, (NP + CHUNK - 1) / CHUNK);          // 512 x 32
        sbls_k2_ga<<<grid, 256, 0, stream>>>(slt, afragG, B2, out);
    } else if (tierB) {
        sbls_slice<<<(NP * 128 + 255) / 256, 256, 0, stream>>>(W2, slt);
        dim3 grid(NN / G, (NP + CHUNK - 1) / CHUNK);
        sbls_k2_bf16<<<grid, 256, 0, stream>>>(slt, B2, colmask, out);
    } else {
        dim3 grid(NN, (NP + 255) / 256);
        sbls_k2_f64<<<grid, 256, 0, stream>>>(W2, B2, colmask, out);
    }
}